// Round 1
// baseline (2205.661 us; speedup 1.0000x reference)
//
#include <hip/hip_runtime.h>
#include <math.h>

#define B_   2
#define R_   4096
#define NRAY 8192
#define NC_  48
#define NI_  48
#define CPL  32
#define HPL  256
#define HID  64

__device__ __forceinline__ float softplusf(float x) {
    return fmaxf(x, 0.0f) + log1pf(expf(-fabsf(x)));
}
__device__ __forceinline__ float sigmoidf(float x) {
    return 1.0f / (1.0f + expf(-x));
}

// ---------- transpose (6,32,256,256) -> (6,256,256,32) channel-last ----------
__global__ void transpose_cl(const float* __restrict__ in, float* __restrict__ out) {
    __shared__ float tile[32][33];
    int blk = blockIdx.x;          // p*2048 + y*8 + xt
    int xt = blk & 7;
    int y  = (blk >> 3) & 255;
    int p  = blk >> 11;
    int tx = threadIdx.x;          // 0..31
    int ty = threadIdx.y;          // 0..7
#pragma unroll
    for (int i = 0; i < 4; ++i) {
        int c = ty + 8 * i;
        tile[c][tx] = in[((p * 32 + c) * 256 + y) * 256 + xt * 32 + tx];
    }
    __syncthreads();
#pragma unroll
    for (int i = 0; i < 4; ++i) {
        int xl = ty + 8 * i;
        out[(((p * 256 + y) * 256) + xt * 32 + xl) * 32 + tx] = tile[tx][xl];
    }
}

__global__ void init_minmax(float* mm) {
    if (threadIdx.x == 0 && blockIdx.x == 0) {
        ((int*)mm)[0] = 0x7f800000;  // +inf
        ((int*)mm)[1] = 0xff800000;  // -inf
    }
}

__global__ void fill_depths_c(const float* __restrict__ noise, float* __restrict__ depths) {
    int gid = blockIdx.x * blockDim.x + threadIdx.x;
    if (gid >= NRAY * NC_) return;
    int s = gid % NC_;
    const float delta = (1.0f - 0.1f) / (NC_ - 1);
    depths[gid] = 0.1f + delta * (float)s + noise[gid] * delta;
}

// ---------- fused plane-sample + MLP: one thread per sample point ----------
// planes projections (derived from INV_PLANES): p0:(x,y)  p1:(x,z)  p2:(z,x)
template<bool CL>
__global__ __launch_bounds__(256) void sample_mlp(
    const float* __restrict__ tex, const float* __restrict__ shp,
    const float* __restrict__ origins, const float* __restrict__ dirs,
    const float* __restrict__ W1, const float* __restrict__ b1,
    const float* __restrict__ W2, const float* __restrict__ b2,
    const float* __restrict__ depths,
    float4* __restrict__ outRGBS)
{
    int gid = blockIdx.x * blockDim.x + threadIdx.x;
    if (gid >= NRAY * NC_) return;
    int ray = gid / NC_;
    int bIdx = ray >> 12;   // ray / 4096

    float ox = origins[ray * 3 + 0], oy = origins[ray * 3 + 1], oz = origins[ray * 3 + 2];
    float dx = dirs[ray * 3 + 0], dy = dirs[ray * 3 + 1], dz = dirs[ray * 3 + 2];
    float invn = 1.0f / sqrtf(dx * dx + dy * dy + dz * dz);
    dx *= invn; dy *= invn; dz *= invn;
    float t = depths[gid];
    float px = ox + t * dx, py = oy + t * dy, pz = oz + t * dz;

    float U[3] = {px, px, pz};
    float V[3] = {py, pz, px};

    int   tapOff[12];
    float tapW[12];
#pragma unroll
    for (int pp = 0; pp < 3; ++pp) {
        float gx = (U[pp] + 1.0f) * 128.0f - 0.5f;
        float gy = (V[pp] + 1.0f) * 128.0f - 0.5f;
        float fgx = floorf(gx), fgy = floorf(gy);
        int x0 = (int)fgx, y0 = (int)fgy;
        float fx = gx - fgx, fy = gy - fgy;
#pragma unroll
        for (int k = 0; k < 4; ++k) {
            int dxk = k & 1, dyk = k >> 1;
            int xi = x0 + dxk, yi = y0 + dyk;
            float w = (dxk ? fx : 1.0f - fx) * (dyk ? fy : 1.0f - fy);
            bool valid = (xi >= 0) && (xi < HPL) && (yi >= 0) && (yi < HPL);
            int xc = min(max(xi, 0), HPL - 1);
            int yc = min(max(yi, 0), HPL - 1);
            int p3 = bIdx * 3 + pp;
            int off;
            if (CL) off = ((p3 * HPL + yc) * HPL + xc) * CPL;
            else    off = p3 * CPL * HPL * HPL + yc * HPL + xc;
            tapOff[pp * 4 + k] = off;
            tapW[pp * 4 + k]   = valid ? w : 0.0f;
        }
    }

    float h[HID];
#pragma unroll
    for (int j = 0; j < HID; ++j) h[j] = b1[j];

    const float inv3 = 1.0f / 3.0f;
#define DO_ROW(XV, ROW) do { float xv_ = (XV) * inv3; const float* wr_ = W1 + (ROW) * HID; \
    _Pragma("unroll") for (int j = 0; j < HID; ++j) h[j] = fmaf(xv_, wr_[j], h[j]); } while (0)

#pragma unroll 1
    for (int g = 0; g < 8; ++g) {
        float at0 = 0, at1 = 0, at2 = 0, at3 = 0, as0 = 0, as1 = 0, as2 = 0, as3 = 0;
#pragma unroll
        for (int kk = 0; kk < 12; ++kk) {
            float w = tapW[kk];
            int off = tapOff[kk];
            float4 ft, fs;
            if (CL) {
                ft = *(const float4*)(tex + off + g * 4);
                fs = *(const float4*)(shp + off + g * 4);
            } else {
                int o = off + (g * 4) * (HPL * HPL);
                ft = make_float4(tex[o], tex[o + 65536], tex[o + 131072], tex[o + 196608]);
                fs = make_float4(shp[o], shp[o + 65536], shp[o + 131072], shp[o + 196608]);
            }
            at0 = fmaf(w, ft.x, at0); at1 = fmaf(w, ft.y, at1);
            at2 = fmaf(w, ft.z, at2); at3 = fmaf(w, ft.w, at3);
            as0 = fmaf(w, fs.x, as0); as1 = fmaf(w, fs.y, as1);
            as2 = fmaf(w, fs.z, as2); as3 = fmaf(w, fs.w, as3);
        }
        int c0 = g * 4;
        DO_ROW(at0, c0 + 0); DO_ROW(at1, c0 + 1); DO_ROW(at2, c0 + 2); DO_ROW(at3, c0 + 3);
        DO_ROW(as0, 32 + c0 + 0); DO_ROW(as1, 32 + c0 + 1); DO_ROW(as2, 32 + c0 + 2); DO_ROW(as3, 32 + c0 + 3);
    }
#undef DO_ROW

    float o0 = b2[0], o1 = b2[1], o2 = b2[2], o3 = b2[3];
#pragma unroll
    for (int j = 0; j < HID; ++j) {
        float hv = softplusf(h[j]);
        o0 = fmaf(hv, W2[j * 4 + 0], o0);
        o1 = fmaf(hv, W2[j * 4 + 1], o1);
        o2 = fmaf(hv, W2[j * 4 + 2], o2);
        o3 = fmaf(hv, W2[j * 4 + 3], o3);
    }
    float r  = sigmoidf(o1) * 1.002f - 0.001f;
    float g2 = sigmoidf(o2) * 1.002f - 0.001f;
    float b3 = sigmoidf(o3) * 1.002f - 0.001f;
    outRGBS[gid] = make_float4(r, g2, b3, o0);
}

// ---------- coarse march + importance resampling: one thread per ray ----------
__global__ void march_importance(const float* __restrict__ depths_c,
                                 const float4* __restrict__ rgbs_c,
                                 const float* __restrict__ impu,
                                 float* __restrict__ depths_f,
                                 float* __restrict__ minmax)
{
    int ray = blockIdx.x * blockDim.x + threadIdx.x;
    if (ray >= NRAY) return;

    float d[NC_], sg[NC_];
    for (int i = 0; i < NC_; ++i) {
        d[i]  = depths_c[ray * NC_ + i];
        sg[i] = rgbs_c[ray * NC_ + i].w;
    }
    float w[NC_ - 1];
    float T = 1.0f;
    for (int i = 0; i < NC_ - 1; ++i) {
        float dl = d[i + 1] - d[i];
        float dens = softplusf(0.5f * (sg[i] + sg[i + 1]) - 1.0f);
        float alpha = 1.0f - expf(-dens * dl);
        w[i] = alpha * T;
        T *= (1.0f - alpha + 1e-10f);
    }
    // wp=[0,w,0]; wmax[i]=max(wp[i],wp[i+1]) (48); wb[i]=0.5*(wmax[i]+wmax[i+1])+0.01 (47)
    float wmax[NC_];
    wmax[0] = w[0];
    for (int i = 1; i < NC_ - 1; ++i) wmax[i] = fmaxf(w[i - 1], w[i]);
    wmax[NC_ - 1] = w[NC_ - 2];
    float wb[NC_ - 1];
    for (int i = 0; i < NC_ - 1; ++i) wb[i] = 0.5f * (wmax[i] + wmax[i + 1]) + 0.01f;
    float zm[NC_ - 1];
    for (int i = 0; i < NC_ - 1; ++i) zm[i] = 0.5f * (d[i] + d[i + 1]);
    // pdf over wb[1..45]
    float s = 0.0f;
    for (int i = 1; i <= 45; ++i) s += wb[i];
    float cdf[46];
    cdf[0] = 0.0f;
    for (int i = 1; i <= 45; ++i) cdf[i] = cdf[i - 1] + wb[i] / s;

    for (int q = 0; q < NI_; ++q) {
        float u = impu[ray * NI_ + q];
        int lo = 0, hi = 46;   // searchsorted right over cdf[0..45]
        while (lo < hi) { int mid = (lo + hi) >> 1; if (cdf[mid] > u) hi = mid; else lo = mid + 1; }
        int ind = lo;
        int below = ind - 1; if (below < 0) below = 0;
        int above = ind;     if (above > 45) above = 45;
        float c0 = cdf[below], c1 = cdf[above];
        float bb0 = zm[below], bb1 = zm[above];
        float den = c1 - c0; if (den < 1e-5f) den = 1.0f;
        float tt = (u - c0) / den;
        depths_f[ray * NI_ + q] = bb0 + tt * (bb1 - bb0);
    }
    atomicMin((int*)minmax,     __float_as_int(d[0]));
    atomicMax(((int*)minmax)+1, __float_as_int(d[NC_ - 1]));
}

// ---------- merge coarse+fine, final march: one thread per ray ----------
__global__ void final_march(const float* __restrict__ depths_c, const float4* __restrict__ rgbs_c,
                            const float* __restrict__ depths_f, const float4* __restrict__ rgbs_f,
                            const float* __restrict__ minmax, float* __restrict__ out)
{
    int ray = blockIdx.x * blockDim.x + threadIdx.x;
    if (ray >= NRAY) return;

    float dc[NC_];
    for (int i = 0; i < NC_; ++i) dc[i] = depths_c[ray * NC_ + i];
    float df[NI_]; int pi[NI_];
    for (int q = 0; q < NI_; ++q) { df[q] = depths_f[ray * NI_ + q]; pi[q] = q; }
    // stable insertion sort of fine depths (coarse already ascending)
    for (int a = 1; a < NI_; ++a) {
        float v = df[a]; int p = pi[a];
        int bq = a - 1;
        while (bq >= 0 && df[bq] > v) { df[bq + 1] = df[bq]; pi[bq + 1] = pi[bq]; --bq; }
        df[bq + 1] = v; pi[bq + 1] = p;
    }

    float T = 1.0f, accR = 0, accG = 0, accB = 0, accD = 0, accW = 0;
    float pdv = 0, pr = 0, pg = 0, pb = 0, ps = 0;
    int i = 0, j = 0;
    for (int k = 0; k < NC_ + NI_; ++k) {
        float cdv, cr, cg, cb, cs;
        bool takeC = (i < NC_) && ((j >= NI_) || (dc[i] <= df[j]));  // ties -> coarse (stable argsort)
        if (takeC) {
            cdv = dc[i];
            float4 v = rgbs_c[ray * NC_ + i];
            cr = v.x; cg = v.y; cb = v.z; cs = v.w; ++i;
        } else {
            cdv = df[j];
            float4 v = rgbs_f[ray * NI_ + pi[j]];
            cr = v.x; cg = v.y; cb = v.z; cs = v.w; ++j;
        }
        if (k > 0) {
            float dl = cdv - pdv;
            float dens = softplusf(0.5f * (ps + cs) - 1.0f);
            float alpha = 1.0f - expf(-dens * dl);
            float wt = alpha * T;
            accR += wt * 0.5f * (pr + cr);
            accG += wt * 0.5f * (pg + cg);
            accB += wt * 0.5f * (pb + cb);
            accD += wt * 0.5f * (pdv + cdv);
            accW += wt;
            T *= (1.0f - alpha + 1e-10f);
        }
        pdv = cdv; pr = cr; pg = cg; pb = cb; ps = cs;
    }
    float q = accD / accW;
    if (!isfinite(q)) q = 0.0f;        // nan_to_num(nan->0, posinf->0), then clip
    q = fminf(fmaxf(q, minmax[0]), minmax[1]);
    out[ray * 3 + 0] = accR * 2.0f - 1.0f;
    out[ray * 3 + 1] = accG * 2.0f - 1.0f;
    out[ray * 3 + 2] = accB * 2.0f - 1.0f;
    out[3 * NRAY + ray] = q;
    out[4 * NRAY + ray] = accW;
}

extern "C" void kernel_launch(void* const* d_in, const int* in_sizes, int n_in,
                              void* d_out, int out_size, void* d_ws, size_t ws_size,
                              hipStream_t stream)
{
    const float* planes_tex = (const float*)d_in[0];
    const float* planes_shp = (const float*)d_in[1];
    const float* origins    = (const float*)d_in[2];
    const float* raydirs    = (const float*)d_in[3];
    const float* W1 = (const float*)d_in[4];
    const float* b1 = (const float*)d_in[5];
    const float* W2 = (const float*)d_in[6];
    const float* b2 = (const float*)d_in[7];
    const float* noise = (const float*)d_in[8];
    const float* impu  = (const float*)d_in[9];
    float* out = (float*)d_out;

    const size_t PLANE_N = (size_t)6 * CPL * HPL * HPL;   // 12,582,912 floats
    const size_t N_SAMP  = (size_t)NRAY * NC_;            // 393,216

    float* ws = (float*)d_ws;
    size_t small_floats = 2 * N_SAMP + 8 * N_SAMP + 2;
    size_t full_floats  = 2 * PLANE_N + small_floats;
    bool use_cl = ws_size >= full_floats * sizeof(float);

    float* tex_cl = ws;
    float* shp_cl = ws + PLANE_N;
    float* base = use_cl ? (ws + 2 * PLANE_N) : ws;
    float*  depths_c = base;
    float*  depths_f = base + N_SAMP;
    float4* rgbs_c   = (float4*)(base + 2 * N_SAMP);
    float4* rgbs_f   = (float4*)(base + 6 * N_SAMP);
    float*  minmax   = base + 10 * N_SAMP;

    if (use_cl) {
        dim3 tb(32, 8);
        hipLaunchKernelGGL(transpose_cl, dim3(6 * 256 * 8), tb, 0, stream, planes_tex, tex_cl);
        hipLaunchKernelGGL(transpose_cl, dim3(6 * 256 * 8), tb, 0, stream, planes_shp, shp_cl);
    }
    hipLaunchKernelGGL(init_minmax, dim3(1), dim3(64), 0, stream, minmax);
    hipLaunchKernelGGL(fill_depths_c, dim3((NRAY * NC_ + 255) / 256), dim3(256), 0, stream, noise, depths_c);

    int nblk = (NRAY * NC_ + 255) / 256;
    if (use_cl) {
        hipLaunchKernelGGL((sample_mlp<true>), dim3(nblk), dim3(256), 0, stream,
            tex_cl, shp_cl, origins, raydirs, W1, b1, W2, b2, depths_c, rgbs_c);
    } else {
        hipLaunchKernelGGL((sample_mlp<false>), dim3(nblk), dim3(256), 0, stream,
            planes_tex, planes_shp, origins, raydirs, W1, b1, W2, b2, depths_c, rgbs_c);
    }
    hipLaunchKernelGGL(march_importance, dim3((NRAY + 63) / 64), dim3(64), 0, stream,
        depths_c, rgbs_c, impu, depths_f, minmax);
    if (use_cl) {
        hipLaunchKernelGGL((sample_mlp<true>), dim3(nblk), dim3(256), 0, stream,
            tex_cl, shp_cl, origins, raydirs, W1, b1, W2, b2, depths_f, rgbs_f);
    } else {
        hipLaunchKernelGGL((sample_mlp<false>), dim3(nblk), dim3(256), 0, stream,
            planes_tex, planes_shp, origins, raydirs, W1, b1, W2, b2, depths_f, rgbs_f);
    }
    hipLaunchKernelGGL(final_march, dim3((NRAY + 63) / 64), dim3(64), 0, stream,
        depths_c, rgbs_c, depths_f, rgbs_f, minmax, out);
}

// Round 2
// 1086.213 us; speedup vs baseline: 2.0306x; 2.0306x over previous
//
#include <hip/hip_runtime.h>
#include <hip/hip_fp16.h>
#include <math.h>

#define B_   2
#define R_   4096
#define NRAY 8192
#define NC_  48
#define NI_  48
#define CPL  32
#define HPL  256
#define HID  64

__device__ __forceinline__ float softplusf(float x) {
    return fmaxf(x, 0.0f) + log1pf(expf(-fabsf(x)));
}
__device__ __forceinline__ float sigmoidf(float x) {
    return 1.0f / (1.0f + expf(-x));
}

// ---------- transpose (6,32,256,256) fp32 -> (6,256,256,32) fp16 channel-last ----------
__global__ void transpose_cl(const float* __restrict__ in, __half* __restrict__ out) {
    __shared__ float tile[32][33];
    int blk = blockIdx.x;          // p*2048 + y*8 + xt
    int xt = blk & 7;
    int y  = (blk >> 3) & 255;
    int p  = blk >> 11;
    int tx = threadIdx.x;          // 0..31
    int ty = threadIdx.y;          // 0..7
#pragma unroll
    for (int i = 0; i < 4; ++i) {
        int c = ty + 8 * i;
        tile[c][tx] = in[((p * 32 + c) * 256 + y) * 256 + xt * 32 + tx];
    }
    __syncthreads();
#pragma unroll
    for (int i = 0; i < 4; ++i) {
        int xl = ty + 8 * i;
        out[(((p * 256 + y) * 256) + xt * 32 + xl) * 32 + tx] = __float2half(tile[tx][xl]);
    }
}

__global__ void init_minmax(float* mm) {
    if (threadIdx.x == 0 && blockIdx.x == 0) {
        ((int*)mm)[0] = 0x7f800000;  // +inf
        ((int*)mm)[1] = 0xff800000;  // -inf
    }
}

__global__ void fill_depths_c(const float* __restrict__ noise, float* __restrict__ depths) {
    int gid = blockIdx.x * blockDim.x + threadIdx.x;
    if (gid >= NRAY * NC_) return;
    int s = gid % NC_;
    const float delta = (1.0f - 0.1f) / (NC_ - 1);
    depths[gid] = 0.1f + delta * (float)s + noise[gid] * delta;
}

// accumulate 8 fp16 channels (packed in a float4) into x[0..7] with weight w
__device__ __forceinline__ void acc8(float4 q, float w, float* x) {
    union { float4 f; __half2 h[4]; } u;
    u.f = q;
#pragma unroll
    for (int i = 0; i < 4; ++i) {
        float2 f = __half22float2(u.h[i]);
        x[2 * i]     = fmaf(w, f.x, x[2 * i]);
        x[2 * i + 1] = fmaf(w, f.y, x[2 * i + 1]);
    }
}

// ---------- fused plane-sample + MLP: one thread per sample point ----------
// projections (from INV_PLANES): p0:(x,y)  p1:(x,z)  p2:(z,x)
// CL=true: fp16 channel-last cache. CL=false: original fp32 (C,H,W) layout.
template<bool CL>
__global__ __launch_bounds__(256) void sample_mlp(
    const void* __restrict__ texv, const void* __restrict__ shpv,
    const float* __restrict__ origins, const float* __restrict__ dirs,
    const float* __restrict__ W1, const float* __restrict__ b1,
    const float* __restrict__ W2, const float* __restrict__ b2,
    const float* __restrict__ depths,
    float4* __restrict__ outRGBS)
{
    int gid = blockIdx.x * blockDim.x + threadIdx.x;
    if (gid >= NRAY * NC_) return;
    int ray = gid / NC_;
    int bIdx = ray >> 12;   // ray / 4096

    float ox = origins[ray * 3 + 0], oy = origins[ray * 3 + 1], oz = origins[ray * 3 + 2];
    float dx = dirs[ray * 3 + 0], dy = dirs[ray * 3 + 1], dz = dirs[ray * 3 + 2];
    float invn = 1.0f / sqrtf(dx * dx + dy * dy + dz * dz);
    dx *= invn; dy *= invn; dz *= invn;
    float t = depths[gid];
    float px = ox + t * dx, py = oy + t * dy, pz = oz + t * dz;

    float U[3] = {px, px, pz};
    float V[3] = {py, pz, px};

    int   tapOff[12];
    float tapW[12];
#pragma unroll
    for (int pp = 0; pp < 3; ++pp) {
        float gx = (U[pp] + 1.0f) * 128.0f - 0.5f;
        float gy = (V[pp] + 1.0f) * 128.0f - 0.5f;
        float fgx = floorf(gx), fgy = floorf(gy);
        int x0 = (int)fgx, y0 = (int)fgy;
        float fx = gx - fgx, fy = gy - fgy;
#pragma unroll
        for (int k = 0; k < 4; ++k) {
            int dxk = k & 1, dyk = k >> 1;
            int xi = x0 + dxk, yi = y0 + dyk;
            float w = (dxk ? fx : 1.0f - fx) * (dyk ? fy : 1.0f - fy);
            bool valid = (xi >= 0) && (xi < HPL) && (yi >= 0) && (yi < HPL);
            int xc = min(max(xi, 0), HPL - 1);
            int yc = min(max(yi, 0), HPL - 1);
            int p3 = bIdx * 3 + pp;
            int off;
            if (CL) off = ((p3 * HPL + yc) * HPL + xc) * CPL;            // half elements
            else    off = p3 * CPL * HPL * HPL + yc * HPL + xc;          // float elements
            tapOff[pp * 4 + k] = off;
            tapW[pp * 4 + k]   = valid ? w : 0.0f;
        }
    }

    // ---- gather: taps outer, full line consumed at once ----
    float x[2 * CPL];
#pragma unroll
    for (int j = 0; j < 2 * CPL; ++j) x[j] = 0.0f;

    if (CL) {
        const __half* texh = (const __half*)texv;
        const __half* shph = (const __half*)shpv;
#pragma unroll
        for (int kk = 0; kk < 12; ++kk) {
            float w  = tapW[kk];
            int  off = tapOff[kk];
            const float4* pt = (const float4*)(texh + off);  // 32 halves = 4 x float4
            const float4* ps = (const float4*)(shph + off);
            float4 t0 = pt[0], t1 = pt[1], t2 = pt[2], t3 = pt[3];
            float4 s0 = ps[0], s1 = ps[1], s2 = ps[2], s3 = ps[3];
            acc8(t0, w, x + 0);  acc8(t1, w, x + 8);
            acc8(t2, w, x + 16); acc8(t3, w, x + 24);
            acc8(s0, w, x + 32); acc8(s1, w, x + 40);
            acc8(s2, w, x + 48); acc8(s3, w, x + 56);
        }
    } else {
        const float* texf = (const float*)texv;
        const float* shpf = (const float*)shpv;
#pragma unroll
        for (int kk = 0; kk < 12; ++kk) {
            float w  = tapW[kk];
            int  off = tapOff[kk];
#pragma unroll
            for (int c = 0; c < CPL; ++c) {
                x[c]       = fmaf(w, texf[off + c * (HPL * HPL)], x[c]);
                x[CPL + c] = fmaf(w, shpf[off + c * (HPL * HPL)], x[CPL + c]);
            }
        }
    }

    // ---- MLP layer 1 (x/3 @ W1 + b1), fully unrolled so x,h stay in VGPRs ----
    float h[HID];
#pragma unroll
    for (int j = 0; j < HID; ++j) h[j] = b1[j];
    const float inv3 = 1.0f / 3.0f;
#pragma unroll
    for (int c = 0; c < 2 * CPL; ++c) {
        float xv = x[c] * inv3;
        const float* wr = W1 + c * HID;
#pragma unroll
        for (int j = 0; j < HID; ++j) h[j] = fmaf(xv, wr[j], h[j]);
    }

    float o0 = b2[0], o1 = b2[1], o2 = b2[2], o3 = b2[3];
#pragma unroll
    for (int j = 0; j < HID; ++j) {
        float hv = softplusf(h[j]);
        o0 = fmaf(hv, W2[j * 4 + 0], o0);
        o1 = fmaf(hv, W2[j * 4 + 1], o1);
        o2 = fmaf(hv, W2[j * 4 + 2], o2);
        o3 = fmaf(hv, W2[j * 4 + 3], o3);
    }
    float r  = sigmoidf(o1) * 1.002f - 0.001f;
    float g2 = sigmoidf(o2) * 1.002f - 0.001f;
    float b3 = sigmoidf(o3) * 1.002f - 0.001f;
    outRGBS[gid] = make_float4(r, g2, b3, o0);
}

// ---------- coarse march + importance resampling: one thread per ray ----------
__global__ void march_importance(const float* __restrict__ depths_c,
                                 const float4* __restrict__ rgbs_c,
                                 const float* __restrict__ impu,
                                 float* __restrict__ depths_f,
                                 float* __restrict__ minmax)
{
    int ray = blockIdx.x * blockDim.x + threadIdx.x;
    if (ray >= NRAY) return;

    float d[NC_], sg[NC_];
    for (int i = 0; i < NC_; ++i) {
        d[i]  = depths_c[ray * NC_ + i];
        sg[i] = rgbs_c[ray * NC_ + i].w;
    }
    float w[NC_ - 1];
    float T = 1.0f;
    for (int i = 0; i < NC_ - 1; ++i) {
        float dl = d[i + 1] - d[i];
        float dens = softplusf(0.5f * (sg[i] + sg[i + 1]) - 1.0f);
        float alpha = 1.0f - expf(-dens * dl);
        w[i] = alpha * T;
        T *= (1.0f - alpha + 1e-10f);
    }
    float wmax[NC_];
    wmax[0] = w[0];
    for (int i = 1; i < NC_ - 1; ++i) wmax[i] = fmaxf(w[i - 1], w[i]);
    wmax[NC_ - 1] = w[NC_ - 2];
    float wb[NC_ - 1];
    for (int i = 0; i < NC_ - 1; ++i) wb[i] = 0.5f * (wmax[i] + wmax[i + 1]) + 0.01f;
    float zm[NC_ - 1];
    for (int i = 0; i < NC_ - 1; ++i) zm[i] = 0.5f * (d[i] + d[i + 1]);
    float s = 0.0f;
    for (int i = 1; i <= 45; ++i) s += wb[i];
    float cdf[46];
    cdf[0] = 0.0f;
    for (int i = 1; i <= 45; ++i) cdf[i] = cdf[i - 1] + wb[i] / s;

    for (int q = 0; q < NI_; ++q) {
        float u = impu[ray * NI_ + q];
        int lo = 0, hi = 46;
        while (lo < hi) { int mid = (lo + hi) >> 1; if (cdf[mid] > u) hi = mid; else lo = mid + 1; }
        int ind = lo;
        int below = ind - 1; if (below < 0) below = 0;
        int above = ind;     if (above > 45) above = 45;
        float c0 = cdf[below], c1 = cdf[above];
        float bb0 = zm[below], bb1 = zm[above];
        float den = c1 - c0; if (den < 1e-5f) den = 1.0f;
        float tt = (u - c0) / den;
        depths_f[ray * NI_ + q] = bb0 + tt * (bb1 - bb0);
    }
    atomicMin((int*)minmax,     __float_as_int(d[0]));
    atomicMax(((int*)minmax)+1, __float_as_int(d[NC_ - 1]));
}

// ---------- merge coarse+fine, final march: one thread per ray ----------
__global__ void final_march(const float* __restrict__ depths_c, const float4* __restrict__ rgbs_c,
                            const float* __restrict__ depths_f, const float4* __restrict__ rgbs_f,
                            const float* __restrict__ minmax, float* __restrict__ out)
{
    int ray = blockIdx.x * blockDim.x + threadIdx.x;
    if (ray >= NRAY) return;

    float dc[NC_];
    for (int i = 0; i < NC_; ++i) dc[i] = depths_c[ray * NC_ + i];
    float df[NI_]; int pi[NI_];
    for (int q = 0; q < NI_; ++q) { df[q] = depths_f[ray * NI_ + q]; pi[q] = q; }
    for (int a = 1; a < NI_; ++a) {
        float v = df[a]; int p = pi[a];
        int bq = a - 1;
        while (bq >= 0 && df[bq] > v) { df[bq + 1] = df[bq]; pi[bq + 1] = pi[bq]; --bq; }
        df[bq + 1] = v; pi[bq + 1] = p;
    }

    float T = 1.0f, accR = 0, accG = 0, accB = 0, accD = 0, accW = 0;
    float pdv = 0, pr = 0, pg = 0, pb = 0, ps = 0;
    int i = 0, j = 0;
    for (int k = 0; k < NC_ + NI_; ++k) {
        float cdv, cr, cg, cb, cs;
        bool takeC = (i < NC_) && ((j >= NI_) || (dc[i] <= df[j]));  // ties -> coarse (stable)
        if (takeC) {
            cdv = dc[i];
            float4 v = rgbs_c[ray * NC_ + i];
            cr = v.x; cg = v.y; cb = v.z; cs = v.w; ++i;
        } else {
            cdv = df[j];
            float4 v = rgbs_f[ray * NI_ + pi[j]];
            cr = v.x; cg = v.y; cb = v.z; cs = v.w; ++j;
        }
        if (k > 0) {
            float dl = cdv - pdv;
            float dens = softplusf(0.5f * (ps + cs) - 1.0f);
            float alpha = 1.0f - expf(-dens * dl);
            float wt = alpha * T;
            accR += wt * 0.5f * (pr + cr);
            accG += wt * 0.5f * (pg + cg);
            accB += wt * 0.5f * (pb + cb);
            accD += wt * 0.5f * (pdv + cdv);
            accW += wt;
            T *= (1.0f - alpha + 1e-10f);
        }
        pdv = cdv; pr = cr; pg = cg; pb = cb; ps = cs;
    }
    float q = accD / accW;
    if (!isfinite(q)) q = 0.0f;
    q = fminf(fmaxf(q, minmax[0]), minmax[1]);
    out[ray * 3 + 0] = accR * 2.0f - 1.0f;
    out[ray * 3 + 1] = accG * 2.0f - 1.0f;
    out[ray * 3 + 2] = accB * 2.0f - 1.0f;
    out[3 * NRAY + ray] = q;
    out[4 * NRAY + ray] = accW;
}

extern "C" void kernel_launch(void* const* d_in, const int* in_sizes, int n_in,
                              void* d_out, int out_size, void* d_ws, size_t ws_size,
                              hipStream_t stream)
{
    const float* planes_tex = (const float*)d_in[0];
    const float* planes_shp = (const float*)d_in[1];
    const float* origins    = (const float*)d_in[2];
    const float* raydirs    = (const float*)d_in[3];
    const float* W1 = (const float*)d_in[4];
    const float* b1 = (const float*)d_in[5];
    const float* W2 = (const float*)d_in[6];
    const float* b2 = (const float*)d_in[7];
    const float* noise = (const float*)d_in[8];
    const float* impu  = (const float*)d_in[9];
    float* out = (float*)d_out;

    const size_t PLANE_N = (size_t)6 * CPL * HPL * HPL;   // 12,582,912 elements per tensor
    const size_t N_SAMP  = (size_t)NRAY * NC_;            // 393,216

    // layout: [tex_cl fp16][shp_cl fp16][small fp32 buffers]
    size_t small_floats = 10 * N_SAMP + 2;
    size_t need_bytes   = 2 * PLANE_N * sizeof(__half) + small_floats * sizeof(float);
    bool use_cl = ws_size >= need_bytes;

    __half* tex_cl = (__half*)d_ws;
    __half* shp_cl = tex_cl + PLANE_N;
    float*  base   = use_cl ? (float*)(shp_cl + PLANE_N) : (float*)d_ws;
    float*  depths_c = base;
    float*  depths_f = base + N_SAMP;
    float4* rgbs_c   = (float4*)(base + 2 * N_SAMP);
    float4* rgbs_f   = (float4*)(base + 6 * N_SAMP);
    float*  minmax   = base + 10 * N_SAMP;

    if (use_cl) {
        dim3 tb(32, 8);
        hipLaunchKernelGGL(transpose_cl, dim3(6 * 256 * 8), tb, 0, stream, planes_tex, tex_cl);
        hipLaunchKernelGGL(transpose_cl, dim3(6 * 256 * 8), tb, 0, stream, planes_shp, shp_cl);
    }
    hipLaunchKernelGGL(init_minmax, dim3(1), dim3(64), 0, stream, minmax);
    hipLaunchKernelGGL(fill_depths_c, dim3((NRAY * NC_ + 255) / 256), dim3(256), 0, stream, noise, depths_c);

    int nblk = (NRAY * NC_ + 255) / 256;
    if (use_cl) {
        hipLaunchKernelGGL((sample_mlp<true>), dim3(nblk), dim3(256), 0, stream,
            (const void*)tex_cl, (const void*)shp_cl, origins, raydirs, W1, b1, W2, b2, depths_c, rgbs_c);
    } else {
        hipLaunchKernelGGL((sample_mlp<false>), dim3(nblk), dim3(256), 0, stream,
            (const void*)planes_tex, (const void*)planes_shp, origins, raydirs, W1, b1, W2, b2, depths_c, rgbs_c);
    }
    hipLaunchKernelGGL(march_importance, dim3((NRAY + 63) / 64), dim3(64), 0, stream,
        depths_c, rgbs_c, impu, depths_f, minmax);
    if (use_cl) {
        hipLaunchKernelGGL((sample_mlp<true>), dim3(nblk), dim3(256), 0, stream,
            (const void*)tex_cl, (const void*)shp_cl, origins, raydirs, W1, b1, W2, b2, depths_f, rgbs_f);
    } else {
        hipLaunchKernelGGL((sample_mlp<false>), dim3(nblk), dim3(256), 0, stream,
            (const void*)planes_tex, (const void*)planes_shp, origins, raydirs, W1, b1, W2, b2, depths_f, rgbs_f);
    }
    hipLaunchKernelGGL(final_march, dim3((NRAY + 63) / 64), dim3(64), 0, stream,
        depths_c, rgbs_c, depths_f, rgbs_f, minmax, out);
}

// Round 3
// 644.142 us; speedup vs baseline: 3.4242x; 1.6863x over previous
//
#include <hip/hip_runtime.h>
#include <hip/hip_fp16.h>
#include <math.h>

#define NRAY 8192
#define NC_  48
#define NI_  48
#define CPL  32
#define HPL  256
#define HID  64
#define NPTS (NRAY * NC_)        // 393216 points per pass

typedef __attribute__((ext_vector_type(8))) short short8;   // 8 bf16
typedef __attribute__((ext_vector_type(4))) float f32x4;

__device__ __forceinline__ float softplusf(float x) {
    return fmaxf(x, 0.0f) + log1pf(expf(-fabsf(x)));
}
__device__ __forceinline__ float sigmoidf(float x) {
    return 1.0f / (1.0f + expf(-x));
}
__device__ __forceinline__ unsigned short f2bf(float f) {
    unsigned u = __float_as_uint(f);
    u += 0x7fffu + ((u >> 16) & 1u);
    return (unsigned short)(u >> 16);
}

// ---- transpose (6,32,256,256) fp32 -> interleaved (6,256,256,64) fp16; choff 0=tex,32=shp ----
__global__ void transpose_cl(const float* __restrict__ in, __half* __restrict__ out, int choff) {
    __shared__ float tile[32][33];
    int blk = blockIdx.x;          // p*2048 + y*8 + xt
    int xt = blk & 7;
    int y  = (blk >> 3) & 255;
    int p  = blk >> 11;
    int tx = threadIdx.x;          // 0..31
    int ty = threadIdx.y;          // 0..7
#pragma unroll
    for (int i = 0; i < 4; ++i) {
        int c = ty + 8 * i;
        tile[c][tx] = in[((p * 32 + c) * 256 + y) * 256 + xt * 32 + tx];
    }
    __syncthreads();
#pragma unroll
    for (int i = 0; i < 4; ++i) {
        int xl = ty + 8 * i;
        out[(size_t)(((p * 256 + y) * 256) + xt * 32 + xl) * 64 + choff + tx] = __float2half(tile[tx][xl]);
    }
}

__global__ void fill_depths_c(const float* __restrict__ noise, float* __restrict__ depths) {
    int gid = blockIdx.x * blockDim.x + threadIdx.x;
    if (gid >= NPTS) return;
    int s = gid % NC_;
    const float delta = (1.0f - 0.1f) / (NC_ - 1);
    depths[gid] = 0.1f + delta * (float)s + noise[gid] * delta;
}

// ---- gather: 4 threads per point, 16 channels each; writes bf16 features (already /3) ----
__global__ __launch_bounds__(256) void gather_feat(
    const __half* __restrict__ planes,     // (6,256,256,64) interleaved fp16
    const float* __restrict__ origins, const float* __restrict__ dirs,
    const float* __restrict__ depths,
    unsigned short* __restrict__ xfeat)    // [NPTS][64] bf16
{
    int gid = blockIdx.x * 256 + threadIdx.x;
    int point = gid >> 2, sub = gid & 3;
    if (point >= NPTS) return;
    int ray = point / NC_;
    int bIdx = ray >> 12;

    float ox = origins[ray * 3 + 0], oy = origins[ray * 3 + 1], oz = origins[ray * 3 + 2];
    float dx = dirs[ray * 3 + 0], dy = dirs[ray * 3 + 1], dz = dirs[ray * 3 + 2];
    float invn = 1.0f / sqrtf(dx * dx + dy * dy + dz * dz);
    dx *= invn; dy *= invn; dz *= invn;
    float t = depths[point];
    float px = ox + t * dx, py = oy + t * dy, pz = oz + t * dz;

    float U[3] = {px, px, pz};
    float V[3] = {py, pz, px};

    int   tapOff[12];
    float tapW[12];
    const float inv3 = 1.0f / 3.0f;
#pragma unroll
    for (int pp = 0; pp < 3; ++pp) {
        float gx = (U[pp] + 1.0f) * 128.0f - 0.5f;
        float gy = (V[pp] + 1.0f) * 128.0f - 0.5f;
        float fgx = floorf(gx), fgy = floorf(gy);
        int x0 = (int)fgx, y0 = (int)fgy;
        float fx = gx - fgx, fy = gy - fgy;
#pragma unroll
        for (int k = 0; k < 4; ++k) {
            int dxk = k & 1, dyk = k >> 1;
            int xi = x0 + dxk, yi = y0 + dyk;
            float w = (dxk ? fx : 1.0f - fx) * (dyk ? fy : 1.0f - fy);
            bool valid = (xi >= 0) && (xi < HPL) && (yi >= 0) && (yi < HPL);
            int xc = min(max(xi, 0), HPL - 1);
            int yc = min(max(yi, 0), HPL - 1);
            int p3 = bIdx * 3 + pp;
            tapOff[pp * 4 + k] = (((p3 * HPL) + yc) * HPL + xc) * 64;
            tapW[pp * 4 + k]   = valid ? w * inv3 : 0.0f;
        }
    }

    float acc[16];
#pragma unroll
    for (int i = 0; i < 16; ++i) acc[i] = 0.0f;

#pragma unroll
    for (int kk = 0; kk < 12; ++kk) {
        float w = tapW[kk];
        const float4* pr = (const float4*)(planes + tapOff[kk] + sub * 16);
        float4 v0 = pr[0], v1 = pr[1];
        union { float4 f; __half2 h[4]; } u0, u1;
        u0.f = v0; u1.f = v1;
#pragma unroll
        for (int i = 0; i < 4; ++i) {
            float2 f0 = __half22float2(u0.h[i]);
            float2 f1 = __half22float2(u1.h[i]);
            acc[2 * i]     = fmaf(w, f0.x, acc[2 * i]);
            acc[2 * i + 1] = fmaf(w, f0.y, acc[2 * i + 1]);
            acc[8 + 2 * i]     = fmaf(w, f1.x, acc[8 + 2 * i]);
            acc[8 + 2 * i + 1] = fmaf(w, f1.y, acc[8 + 2 * i + 1]);
        }
    }

    unsigned short u16[16];
#pragma unroll
    for (int i = 0; i < 16; ++i) u16[i] = f2bf(acc[i]);
    uint4* dst = (uint4*)(xfeat + (size_t)point * 64 + sub * 16);
    dst[0] = *(uint4*)(u16);
    dst[1] = *(uint4*)(u16 + 8);
}

// ---- MFMA MLP: wave handles 16 points x 64 hidden; layer2 epilogue with lane butterfly ----
__global__ __launch_bounds__(256) void mlp_decode(
    const unsigned short* __restrict__ xfeat,
    const float* __restrict__ W1, const float* __restrict__ b1,
    const float* __restrict__ W2, const float* __restrict__ b2,
    float4* __restrict__ outRGBS)
{
    int lane = threadIdx.x & 63;
    int wave = threadIdx.x >> 6;
    int m0 = blockIdx.x * 64 + wave * 16;
    int g = lane >> 4, c = lane & 15;

    // B fragments of W1 (k = kb*32 + g*8 + j, n = t*16 + c)
    short8 bfr[4][2];
#pragma unroll
    for (int t = 0; t < 4; ++t)
#pragma unroll
        for (int kb = 0; kb < 2; ++kb) {
            short8 bb;
#pragma unroll
            for (int j = 0; j < 8; ++j)
                bb[j] = (short)f2bf(W1[(kb * 32 + g * 8 + j) * HID + t * 16 + c]);
            bfr[t][kb] = bb;
        }
    float w2r[4][4];
#pragma unroll
    for (int t = 0; t < 4; ++t)
#pragma unroll
        for (int o = 0; o < 4; ++o) w2r[t][o] = W2[(t * 16 + c) * 4 + o];
    float b1v[4];
#pragma unroll
    for (int t = 0; t < 4; ++t) b1v[t] = b1[t * 16 + c];

    // A fragments (m = m0 + c, k = kb*32 + g*8 + j)
    short8 a0 = *(const short8*)(xfeat + (size_t)(m0 + c) * 64 + g * 8);
    short8 a1 = *(const short8*)(xfeat + (size_t)(m0 + c) * 64 + 32 + g * 8);

    f32x4 accv[4];
#pragma unroll
    for (int t = 0; t < 4; ++t) {
        f32x4 z = {0.f, 0.f, 0.f, 0.f};
        z = __builtin_amdgcn_mfma_f32_16x16x32_bf16(a0, bfr[t][0], z, 0, 0, 0);
        z = __builtin_amdgcn_mfma_f32_16x16x32_bf16(a1, bfr[t][1], z, 0, 0, 0);
        accv[t] = z;
    }

    // epilogue: h -> softplus -> partial layer2, reduce over the 16 lanes of each row-group
    float o[4][4];
#pragma unroll
    for (int r = 0; r < 4; ++r)
#pragma unroll
        for (int q = 0; q < 4; ++q) o[r][q] = 0.0f;
#pragma unroll
    for (int t = 0; t < 4; ++t)
#pragma unroll
        for (int r = 0; r < 4; ++r) {
            float h = accv[t][r] + b1v[t];
            float sp = softplusf(h);
#pragma unroll
            for (int q = 0; q < 4; ++q) o[r][q] = fmaf(sp, w2r[t][q], o[r][q]);
        }
#pragma unroll
    for (int mask = 1; mask <= 8; mask <<= 1)
#pragma unroll
        for (int r = 0; r < 4; ++r)
#pragma unroll
            for (int q = 0; q < 4; ++q) o[r][q] += __shfl_xor(o[r][q], mask, 64);

    if (c == 0) {
#pragma unroll
        for (int r = 0; r < 4; ++r) {
            int pt = m0 + g * 4 + r;
            float sig = o[r][0] + b2[0];
            float rr = sigmoidf(o[r][1] + b2[1]) * 1.002f - 0.001f;
            float gg = sigmoidf(o[r][2] + b2[2]) * 1.002f - 0.001f;
            float bb = sigmoidf(o[r][3] + b2[3]) * 1.002f - 0.001f;
            outRGBS[pt] = make_float4(rr, gg, bb, sig);
        }
    }
}

// ---- coarse march -> cdf + z_mid per ray (stride 96: [0..45]=cdf, [46..92]=zm) ----
__global__ void cdf_build(const float* __restrict__ depths_c,
                          const float4* __restrict__ rgbs_c,
                          float* __restrict__ cdfzm)
{
    int ray = blockIdx.x * blockDim.x + threadIdx.x;
    if (ray >= NRAY) return;
    float w[NC_ - 1];
    float* outz = cdfzm + (size_t)ray * 96 + 46;
    float T = 1.0f;
    float dprev = depths_c[ray * NC_], sprev = rgbs_c[ray * NC_].w;
#pragma unroll
    for (int i = 0; i < NC_ - 1; ++i) {
        float dn = depths_c[ray * NC_ + i + 1];
        float sn = rgbs_c[ray * NC_ + i + 1].w;
        outz[i] = 0.5f * (dprev + dn);
        float dl = dn - dprev;
        float dens = softplusf(0.5f * (sprev + sn) - 1.0f);
        float alpha = 1.0f - expf(-dens * dl);
        w[i] = alpha * T;
        T *= (1.0f - alpha + 1e-10f);
        dprev = dn; sprev = sn;
    }
    float wmax[NC_];
    wmax[0] = w[0];
#pragma unroll
    for (int i = 1; i < NC_ - 1; ++i) wmax[i] = fmaxf(w[i - 1], w[i]);
    wmax[NC_ - 1] = w[NC_ - 2];
    float wbv[NC_ - 1];
#pragma unroll
    for (int i = 0; i < NC_ - 1; ++i) wbv[i] = 0.5f * (wmax[i] + wmax[i + 1]) + 0.01f;
    float s = 0.0f;
#pragma unroll
    for (int i = 1; i <= 45; ++i) s += wbv[i];
    float* outc = cdfzm + (size_t)ray * 96;
    outc[0] = 0.0f;
    float cum = 0.0f;
#pragma unroll
    for (int i = 1; i <= 45; ++i) { cum += wbv[i] / s; outc[i] = cum; }
}

// ---- importance sampling: one thread per (ray, q) ----
__global__ void imp_sample(const float* __restrict__ cdfzm,
                           const float* __restrict__ impu,
                           float* __restrict__ depths_f)
{
    int gid = blockIdx.x * blockDim.x + threadIdx.x;
    if (gid >= NRAY * NI_) return;
    int ray = gid / NI_;
    const float* cdf = cdfzm + (size_t)ray * 96;
    const float* zm  = cdf + 46;
    float u = impu[gid];
    int lo = 0, hi = 46;
    while (lo < hi) { int mid = (lo + hi) >> 1; if (cdf[mid] > u) hi = mid; else lo = mid + 1; }
    int below = max(lo - 1, 0);
    int above = min(lo, 45);
    float c0 = cdf[below], c1 = cdf[above];
    float b0 = zm[below], b1v = zm[above];
    float den = c1 - c0; if (den < 1e-5f) den = 1.0f;
    depths_f[gid] = b0 + (u - c0) / den * (b1v - b0);
}

// ---- global depth min/max (single block) ----
__global__ __launch_bounds__(1024) void minmax_reduce(const float* __restrict__ depths_c,
                                                      float* __restrict__ minmax)
{
    int tid = threadIdx.x;
    float mn = INFINITY, mx = -INFINITY;
    for (int r = tid; r < NRAY; r += 1024) {
        mn = fminf(mn, depths_c[r * NC_]);
        mx = fmaxf(mx, depths_c[r * NC_ + NC_ - 1]);
    }
#pragma unroll
    for (int mask = 1; mask <= 32; mask <<= 1) {
        mn = fminf(mn, __shfl_xor(mn, mask, 64));
        mx = fmaxf(mx, __shfl_xor(mx, mask, 64));
    }
    __shared__ float smn[16], smx[16];
    if ((tid & 63) == 0) { smn[tid >> 6] = mn; smx[tid >> 6] = mx; }
    __syncthreads();
    if (tid == 0) {
        for (int i = 1; i < 16; ++i) { mn = fminf(mn, smn[i]); mx = fmaxf(mx, smx[i]); }
        minmax[0] = mn; minmax[1] = mx;
    }
}

// ---- merge coarse+fine and final march; per-ray arrays live in padded LDS ----
#define FM_RAYS 64
__global__ __launch_bounds__(64) void final_march(
    const float* __restrict__ depths_c, const float4* __restrict__ rgbs_c,
    const float* __restrict__ depths_f, const float4* __restrict__ rgbs_f,
    const float* __restrict__ minmax, float* __restrict__ out)
{
    __shared__ float s_dc[FM_RAYS][NC_ + 1];
    __shared__ float s_df[FM_RAYS][NI_ + 1];
    __shared__ int   s_pi[FM_RAYS][NI_ + 1];
    int r0 = blockIdx.x * FM_RAYS;
    int tid = threadIdx.x;
    for (int idx = tid; idx < FM_RAYS * NC_; idx += 64) {
        int rr = idx / NC_, ii = idx % NC_;
        s_dc[rr][ii] = depths_c[(r0 + rr) * NC_ + ii];
        s_df[rr][ii] = depths_f[(r0 + rr) * NI_ + ii];
    }
    __syncthreads();

    int ray = r0 + tid;
    float* dfr = s_df[tid];
    int*   pir = s_pi[tid];
    for (int i = 0; i < NI_; ++i) pir[i] = i;
    for (int a = 1; a < NI_; ++a) {
        float v = dfr[a]; int p = pir[a];
        int bq = a - 1;
        while (bq >= 0 && dfr[bq] > v) { dfr[bq + 1] = dfr[bq]; pir[bq + 1] = pir[bq]; --bq; }
        dfr[bq + 1] = v; pir[bq + 1] = p;
    }

    const float* dcr = s_dc[tid];
    float T = 1.0f, accR = 0, accG = 0, accB = 0, accD = 0, accW = 0;
    float pdv = 0, pr = 0, pg = 0, pb = 0, ps = 0;
    int i = 0, j = 0;
    for (int k = 0; k < NC_ + NI_; ++k) {
        float cdv, cr, cg, cb, cs;
        bool takeC = (i < NC_) && ((j >= NI_) || (dcr[i] <= dfr[j]));  // ties -> coarse (stable)
        if (takeC) {
            cdv = dcr[i];
            float4 v = rgbs_c[ray * NC_ + i];
            cr = v.x; cg = v.y; cb = v.z; cs = v.w; ++i;
        } else {
            cdv = dfr[j];
            float4 v = rgbs_f[ray * NI_ + pir[j]];
            cr = v.x; cg = v.y; cb = v.z; cs = v.w; ++j;
        }
        if (k > 0) {
            float dl = cdv - pdv;
            float dens = softplusf(0.5f * (ps + cs) - 1.0f);
            float alpha = 1.0f - expf(-dens * dl);
            float wt = alpha * T;
            accR += wt * 0.5f * (pr + cr);
            accG += wt * 0.5f * (pg + cg);
            accB += wt * 0.5f * (pb + cb);
            accD += wt * 0.5f * (pdv + cdv);
            accW += wt;
            T *= (1.0f - alpha + 1e-10f);
        }
        pdv = cdv; pr = cr; pg = cg; pb = cb; ps = cs;
    }
    float q = accD / accW;
    if (!isfinite(q)) q = 0.0f;
    q = fminf(fmaxf(q, minmax[0]), minmax[1]);
    out[ray * 3 + 0] = accR * 2.0f - 1.0f;
    out[ray * 3 + 1] = accG * 2.0f - 1.0f;
    out[ray * 3 + 2] = accB * 2.0f - 1.0f;
    out[3 * NRAY + ray] = q;
    out[4 * NRAY + ray] = accW;
}

extern "C" void kernel_launch(void* const* d_in, const int* in_sizes, int n_in,
                              void* d_out, int out_size, void* d_ws, size_t ws_size,
                              hipStream_t stream)
{
    const float* planes_tex = (const float*)d_in[0];
    const float* planes_shp = (const float*)d_in[1];
    const float* origins    = (const float*)d_in[2];
    const float* raydirs    = (const float*)d_in[3];
    const float* W1 = (const float*)d_in[4];
    const float* b1 = (const float*)d_in[5];
    const float* W2 = (const float*)d_in[6];
    const float* b2 = (const float*)d_in[7];
    const float* noise = (const float*)d_in[8];
    const float* impu  = (const float*)d_in[9];
    float* out = (float*)d_out;

    // workspace layout (total 116,391,944 B, equal to the previously-proven budget):
    //   [0, 50.3MB)       planes_cl  : interleaved fp16 (6,256,256,64)
    //   [50.3, 100.7MB)   xfeat      : bf16 [NPTS][64]; cdfzm + minmax aliased inside
    //   [100.7MB, ...)    depths_c, depths_f, rgbs_c, rgbs_f
    char* ws = (char*)d_ws;
    __half*         planes_cl = (__half*)ws;
    unsigned short* xfeat     = (unsigned short*)(ws + 50331648);
    float*          cdfzm     = (float*)(ws + 50331648);            // dead before fine gather
    float*          minmax    = (float*)(ws + 50331648 + 8388608);  // written after fine mlp
    float*  depths_c = (float*)(ws + 100663296);
    float*  depths_f = depths_c + NPTS;
    float4* rgbs_c   = (float4*)(depths_f + NPTS);
    float4* rgbs_f   = rgbs_c + NPTS;

    dim3 tb(32, 8);
    transpose_cl<<<dim3(6 * 256 * 8), tb, 0, stream>>>(planes_tex, planes_cl, 0);
    transpose_cl<<<dim3(6 * 256 * 8), tb, 0, stream>>>(planes_shp, planes_cl, 32);
    fill_depths_c<<<dim3((NPTS + 255) / 256), dim3(256), 0, stream>>>(noise, depths_c);

    gather_feat<<<dim3(NPTS / 64), dim3(256), 0, stream>>>(planes_cl, origins, raydirs, depths_c, xfeat);
    mlp_decode<<<dim3(NPTS / 64), dim3(256), 0, stream>>>(xfeat, W1, b1, W2, b2, rgbs_c);

    cdf_build<<<dim3(NRAY / 256), dim3(256), 0, stream>>>(depths_c, rgbs_c, cdfzm);
    imp_sample<<<dim3((NRAY * NI_ + 255) / 256), dim3(256), 0, stream>>>(cdfzm, impu, depths_f);

    gather_feat<<<dim3(NPTS / 64), dim3(256), 0, stream>>>(planes_cl, origins, raydirs, depths_f, xfeat);
    mlp_decode<<<dim3(NPTS / 64), dim3(256), 0, stream>>>(xfeat, W1, b1, W2, b2, rgbs_f);

    minmax_reduce<<<dim3(1), dim3(1024), 0, stream>>>(depths_c, minmax);
    final_march<<<dim3(NRAY / FM_RAYS), dim3(64), 0, stream>>>(depths_c, rgbs_c, depths_f, rgbs_f, minmax, out);
}

// Round 4
// 480.653 us; speedup vs baseline: 4.5889x; 1.3401x over previous
//
#include <hip/hip_runtime.h>
#include <hip/hip_fp16.h>
#include <math.h>

#define NRAY 8192
#define NC_  48
#define NI_  48
#define CPL  32
#define HPL  256
#define HID  64
#define NPTS (NRAY * NC_)        // 393216 points per pass

typedef __attribute__((ext_vector_type(8))) short short8;   // 8 bf16
typedef __attribute__((ext_vector_type(4))) float f32x4;

__device__ __forceinline__ float softplusf(float x) {
    return fmaxf(x, 0.0f) + log1pf(expf(-fabsf(x)));
}
__device__ __forceinline__ float sigmoidf(float x) {
    return 1.0f / (1.0f + expf(-x));
}
__device__ __forceinline__ unsigned short f2bf(float f) {
    unsigned u = __float_as_uint(f);
    u += 0x7fffu + ((u >> 16) & 1u);
    return (unsigned short)(u >> 16);
}

// ---- transpose (6,32,256,256) fp32 -> interleaved (6,256,256,64) fp16; choff 0=tex,32=shp ----
__global__ void transpose_cl(const float* __restrict__ in, __half* __restrict__ out, int choff) {
    __shared__ float tile[32][33];
    int blk = blockIdx.x;          // p*2048 + y*8 + xt
    int xt = blk & 7;
    int y  = (blk >> 3) & 255;
    int p  = blk >> 11;
    int tx = threadIdx.x;          // 0..31
    int ty = threadIdx.y;          // 0..7
#pragma unroll
    for (int i = 0; i < 4; ++i) {
        int c = ty + 8 * i;
        tile[c][tx] = in[((p * 32 + c) * 256 + y) * 256 + xt * 32 + tx];
    }
    __syncthreads();
#pragma unroll
    for (int i = 0; i < 4; ++i) {
        int xl = ty + 8 * i;
        out[(size_t)(((p * 256 + y) * 256) + xt * 32 + xl) * 64 + choff + tx] = __float2half(tile[tx][xl]);
    }
}

__global__ void fill_depths_c(const float* __restrict__ noise, float* __restrict__ depths) {
    int gid = blockIdx.x * blockDim.x + threadIdx.x;
    if (gid >= NPTS) return;
    int s = gid % NC_;
    const float delta = (1.0f - 0.1f) / (NC_ - 1);
    depths[gid] = 0.1f + delta * (float)s + noise[gid] * delta;
}

// ---- gather: 4 threads per point, 16 channels each; writes bf16 features (already /3) ----
__global__ __launch_bounds__(256) void gather_feat(
    const __half* __restrict__ planes,     // (6,256,256,64) interleaved fp16
    const float* __restrict__ origins, const float* __restrict__ dirs,
    const float* __restrict__ depths,
    unsigned short* __restrict__ xfeat)    // [NPTS][64] bf16
{
    int gid = blockIdx.x * 256 + threadIdx.x;
    int point = gid >> 2, sub = gid & 3;
    if (point >= NPTS) return;
    int ray = point / NC_;
    int bIdx = ray >> 12;

    float ox = origins[ray * 3 + 0], oy = origins[ray * 3 + 1], oz = origins[ray * 3 + 2];
    float dx = dirs[ray * 3 + 0], dy = dirs[ray * 3 + 1], dz = dirs[ray * 3 + 2];
    float invn = 1.0f / sqrtf(dx * dx + dy * dy + dz * dz);
    dx *= invn; dy *= invn; dz *= invn;
    float t = depths[point];
    float px = ox + t * dx, py = oy + t * dy, pz = oz + t * dz;

    float U[3] = {px, px, pz};
    float V[3] = {py, pz, px};

    int   tapOff[12];
    float tapW[12];
    const float inv3 = 1.0f / 3.0f;
#pragma unroll
    for (int pp = 0; pp < 3; ++pp) {
        float gx = (U[pp] + 1.0f) * 128.0f - 0.5f;
        float gy = (V[pp] + 1.0f) * 128.0f - 0.5f;
        float fgx = floorf(gx), fgy = floorf(gy);
        int x0 = (int)fgx, y0 = (int)fgy;
        float fx = gx - fgx, fy = gy - fgy;
#pragma unroll
        for (int k = 0; k < 4; ++k) {
            int dxk = k & 1, dyk = k >> 1;
            int xi = x0 + dxk, yi = y0 + dyk;
            float w = (dxk ? fx : 1.0f - fx) * (dyk ? fy : 1.0f - fy);
            bool valid = (xi >= 0) && (xi < HPL) && (yi >= 0) && (yi < HPL);
            int xc = min(max(xi, 0), HPL - 1);
            int yc = min(max(yi, 0), HPL - 1);
            int p3 = bIdx * 3 + pp;
            tapOff[pp * 4 + k] = (((p3 * HPL) + yc) * HPL + xc) * 64;
            tapW[pp * 4 + k]   = valid ? w * inv3 : 0.0f;
        }
    }

    float acc[16];
#pragma unroll
    for (int i = 0; i < 16; ++i) acc[i] = 0.0f;

#pragma unroll
    for (int kk = 0; kk < 12; ++kk) {
        float w = tapW[kk];
        const float4* pr = (const float4*)(planes + tapOff[kk] + sub * 16);
        float4 v0 = pr[0], v1 = pr[1];
        union { float4 f; __half2 h[4]; } u0, u1;
        u0.f = v0; u1.f = v1;
#pragma unroll
        for (int i = 0; i < 4; ++i) {
            float2 f0 = __half22float2(u0.h[i]);
            float2 f1 = __half22float2(u1.h[i]);
            acc[2 * i]     = fmaf(w, f0.x, acc[2 * i]);
            acc[2 * i + 1] = fmaf(w, f0.y, acc[2 * i + 1]);
            acc[8 + 2 * i]     = fmaf(w, f1.x, acc[8 + 2 * i]);
            acc[8 + 2 * i + 1] = fmaf(w, f1.y, acc[8 + 2 * i + 1]);
        }
    }

    unsigned short u16[16];
#pragma unroll
    for (int i = 0; i < 16; ++i) u16[i] = f2bf(acc[i]);
    uint4* dst = (uint4*)(xfeat + (size_t)point * 64 + sub * 16);
    dst[0] = *(uint4*)(u16);
    dst[1] = *(uint4*)(u16 + 8);
}

// ---- MFMA MLP: wave handles 16 points x 64 hidden; layer2 epilogue with lane butterfly ----
__global__ __launch_bounds__(256) void mlp_decode(
    const unsigned short* __restrict__ xfeat,
    const float* __restrict__ W1, const float* __restrict__ b1,
    const float* __restrict__ W2, const float* __restrict__ b2,
    float4* __restrict__ outRGBS)
{
    int lane = threadIdx.x & 63;
    int wave = threadIdx.x >> 6;
    int m0 = blockIdx.x * 64 + wave * 16;
    int g = lane >> 4, c = lane & 15;

    // B fragments of W1 (k = kb*32 + g*8 + j, n = t*16 + c)
    short8 bfr[4][2];
#pragma unroll
    for (int t = 0; t < 4; ++t)
#pragma unroll
        for (int kb = 0; kb < 2; ++kb) {
            short8 bb;
#pragma unroll
            for (int j = 0; j < 8; ++j)
                bb[j] = (short)f2bf(W1[(kb * 32 + g * 8 + j) * HID + t * 16 + c]);
            bfr[t][kb] = bb;
        }
    float w2r[4][4];
#pragma unroll
    for (int t = 0; t < 4; ++t)
#pragma unroll
        for (int o = 0; o < 4; ++o) w2r[t][o] = W2[(t * 16 + c) * 4 + o];
    float b1v[4];
#pragma unroll
    for (int t = 0; t < 4; ++t) b1v[t] = b1[t * 16 + c];

    // A fragments (m = m0 + c, k = kb*32 + g*8 + j)
    short8 a0 = *(const short8*)(xfeat + (size_t)(m0 + c) * 64 + g * 8);
    short8 a1 = *(const short8*)(xfeat + (size_t)(m0 + c) * 64 + 32 + g * 8);

    f32x4 accv[4];
#pragma unroll
    for (int t = 0; t < 4; ++t) {
        f32x4 z = {0.f, 0.f, 0.f, 0.f};
        z = __builtin_amdgcn_mfma_f32_16x16x32_bf16(a0, bfr[t][0], z, 0, 0, 0);
        z = __builtin_amdgcn_mfma_f32_16x16x32_bf16(a1, bfr[t][1], z, 0, 0, 0);
        accv[t] = z;
    }

    // epilogue: h -> softplus -> partial layer2, reduce over the 16 lanes of each row-group
    float o[4][4];
#pragma unroll
    for (int r = 0; r < 4; ++r)
#pragma unroll
        for (int q = 0; q < 4; ++q) o[r][q] = 0.0f;
#pragma unroll
    for (int t = 0; t < 4; ++t)
#pragma unroll
        for (int r = 0; r < 4; ++r) {
            float h = accv[t][r] + b1v[t];
            float sp = softplusf(h);
#pragma unroll
            for (int q = 0; q < 4; ++q) o[r][q] = fmaf(sp, w2r[t][q], o[r][q]);
        }
#pragma unroll
    for (int mask = 1; mask <= 8; mask <<= 1)
#pragma unroll
        for (int r = 0; r < 4; ++r)
#pragma unroll
            for (int q = 0; q < 4; ++q) o[r][q] += __shfl_xor(o[r][q], mask, 64);

    if (c == 0) {
#pragma unroll
        for (int r = 0; r < 4; ++r) {
            int pt = m0 + g * 4 + r;
            float sig = o[r][0] + b2[0];
            float rr = sigmoidf(o[r][1] + b2[1]) * 1.002f - 0.001f;
            float gg = sigmoidf(o[r][2] + b2[2]) * 1.002f - 0.001f;
            float bb = sigmoidf(o[r][3] + b2[3]) * 1.002f - 0.001f;
            outRGBS[pt] = make_float4(rr, gg, bb, sig);
        }
    }
}

// ---- coarse march -> cdf + z_mid per ray (stride 96: [0..45]=cdf, [46..92]=zm) ----
__global__ void cdf_build(const float* __restrict__ depths_c,
                          const float4* __restrict__ rgbs_c,
                          float* __restrict__ cdfzm)
{
    int ray = blockIdx.x * blockDim.x + threadIdx.x;
    if (ray >= NRAY) return;
    float w[NC_ - 1];
    float* outz = cdfzm + (size_t)ray * 96 + 46;
    float T = 1.0f;
    float dprev = depths_c[ray * NC_], sprev = rgbs_c[ray * NC_].w;
#pragma unroll
    for (int i = 0; i < NC_ - 1; ++i) {
        float dn = depths_c[ray * NC_ + i + 1];
        float sn = rgbs_c[ray * NC_ + i + 1].w;
        outz[i] = 0.5f * (dprev + dn);
        float dl = dn - dprev;
        float dens = softplusf(0.5f * (sprev + sn) - 1.0f);
        float alpha = 1.0f - expf(-dens * dl);
        w[i] = alpha * T;
        T *= (1.0f - alpha + 1e-10f);
        dprev = dn; sprev = sn;
    }
    float wmax[NC_];
    wmax[0] = w[0];
#pragma unroll
    for (int i = 1; i < NC_ - 1; ++i) wmax[i] = fmaxf(w[i - 1], w[i]);
    wmax[NC_ - 1] = w[NC_ - 2];
    float wbv[NC_ - 1];
#pragma unroll
    for (int i = 0; i < NC_ - 1; ++i) wbv[i] = 0.5f * (wmax[i] + wmax[i + 1]) + 0.01f;
    float s = 0.0f;
#pragma unroll
    for (int i = 1; i <= 45; ++i) s += wbv[i];
    float* outc = cdfzm + (size_t)ray * 96;
    outc[0] = 0.0f;
    float cum = 0.0f;
#pragma unroll
    for (int i = 1; i <= 45; ++i) { cum += wbv[i] / s; outc[i] = cum; }
}

// ---- importance sampling: one thread per (ray, q) ----
__global__ void imp_sample(const float* __restrict__ cdfzm,
                           const float* __restrict__ impu,
                           float* __restrict__ depths_f)
{
    int gid = blockIdx.x * blockDim.x + threadIdx.x;
    if (gid >= NRAY * NI_) return;
    int ray = gid / NI_;
    const float* cdf = cdfzm + (size_t)ray * 96;
    const float* zm  = cdf + 46;
    float u = impu[gid];
    int lo = 0, hi = 46;
    while (lo < hi) { int mid = (lo + hi) >> 1; if (cdf[mid] > u) hi = mid; else lo = mid + 1; }
    int below = max(lo - 1, 0);
    int above = min(lo, 45);
    float c0 = cdf[below], c1 = cdf[above];
    float b0 = zm[below], b1v = zm[above];
    float den = c1 - c0; if (den < 1e-5f) den = 1.0f;
    depths_f[gid] = b0 + (u - c0) / den * (b1v - b0);
}

// ---- global depth min/max (single block) ----
__global__ __launch_bounds__(1024) void minmax_reduce(const float* __restrict__ depths_c,
                                                      float* __restrict__ minmax)
{
    int tid = threadIdx.x;
    float mn = INFINITY, mx = -INFINITY;
    for (int r = tid; r < NRAY; r += 1024) {
        mn = fminf(mn, depths_c[r * NC_]);
        mx = fmaxf(mx, depths_c[r * NC_ + NC_ - 1]);
    }
#pragma unroll
    for (int mask = 1; mask <= 32; mask <<= 1) {
        mn = fminf(mn, __shfl_xor(mn, mask, 64));
        mx = fmaxf(mx, __shfl_xor(mx, mask, 64));
    }
    __shared__ float smn[16], smx[16];
    if ((tid & 63) == 0) { smn[tid >> 6] = mn; smx[tid >> 6] = mx; }
    __syncthreads();
    if (tid == 0) {
        for (int i = 1; i < 16; ++i) { mn = fminf(mn, smn[i]); mx = fmaxf(mx, smx[i]); }
        minmax[0] = mn; minmax[1] = mx;
    }
}

// ---- merge + final march: ONE WAVE PER RAY, lane-parallel rank-merge + scan ----
#define FM_WAVES 4
__global__ __launch_bounds__(256) void final_march(
    const float* __restrict__ depths_c, const float4* __restrict__ rgbs_c,
    const float* __restrict__ depths_f, const float4* __restrict__ rgbs_f,
    const float* __restrict__ minmax, float* __restrict__ out)
{
    __shared__ float s_dc[FM_WAVES][NC_];
    __shared__ float s_df[FM_WAVES][NI_];
    __shared__ float s_md[FM_WAVES][96];
    __shared__ float s_ms[FM_WAVES][96];
    __shared__ float s_mr[FM_WAVES][96];
    __shared__ float s_mg[FM_WAVES][96];
    __shared__ float s_mb[FM_WAVES][96];

    int wave = threadIdx.x >> 6, lane = threadIdx.x & 63;
    int ray = blockIdx.x * FM_WAVES + wave;
    float* dcp = s_dc[wave];
    float* dfp = s_df[wave];
    float* mdp = s_md[wave];
    float* msp = s_ms[wave];
    float* mrp = s_mr[wave];
    float* mgp = s_mg[wave];
    float* mbp = s_mb[wave];

    float dcv = 0.f, dfv = 0.f;
    float4 c4 = make_float4(0, 0, 0, 0), f4 = make_float4(0, 0, 0, 0);
    if (lane < NC_) {
        dcv = depths_c[ray * NC_ + lane];
        dfv = depths_f[ray * NI_ + lane];
        dcp[lane] = dcv;
        dfp[lane] = dfv;
        c4 = rgbs_c[ray * NC_ + lane];
        f4 = rgbs_f[ray * NI_ + lane];
    }
    __syncthreads();

    if (lane < NC_) {
        int cntC = 0, rankF = 0, cntCle = 0;
#pragma unroll
        for (int j = 0; j < NC_; ++j) {
            float dfj = dfp[j];
            float dcj = dcp[j];
            cntC   += (dfj < dcv) ? 1 : 0;
            rankF  += ((dfj < dfv) || (dfj == dfv && j < lane)) ? 1 : 0;
            cntCle += (dcj <= dfv) ? 1 : 0;
        }
        int posC = lane + cntC;          // stable: coarse before equal fine
        int posF = rankF + cntCle;
        mdp[posC] = dcv; msp[posC] = c4.w; mrp[posC] = c4.x; mgp[posC] = c4.y; mbp[posC] = c4.z;
        mdp[posF] = dfv; msp[posF] = f4.w; mrp[posF] = f4.x; mgp[posF] = f4.y; mbp[posF] = f4.z;
    }
    __syncthreads();

    // lane handles intervals k0=2*lane, k1=2*lane+1 (valid if < 95)
    int k0 = 2 * lane;
    int i0 = min(k0, 95), i1 = min(k0 + 1, 95), i2 = min(k0 + 2, 95);
    float d0 = mdp[i0], d1 = mdp[i1], d2 = mdp[i2];
    float sg0 = msp[i0], sg1 = msp[i1], sg2 = msp[i2];
    float r0 = mrp[i0], r1 = mrp[i1], r2 = mrp[i2];
    float g0 = mgp[i0], g1 = mgp[i1], g2 = mgp[i2];
    float bb0 = mbp[i0], bb1 = mbp[i1], bb2 = mbp[i2];

    bool v0 = (k0 < 95), v1 = (k0 + 1 < 95);
    float a0 = 0.f, a1 = 0.f, f0 = 1.f, f1 = 1.f;
    if (v0) {
        float dens = softplusf(0.5f * (sg0 + sg1) - 1.0f);
        a0 = 1.0f - expf(-dens * (d1 - d0));
        f0 = 1.0f - a0 + 1e-10f;
    }
    if (v1) {
        float dens = softplusf(0.5f * (sg1 + sg2) - 1.0f);
        a1 = 1.0f - expf(-dens * (d2 - d1));
        f1 = 1.0f - a1 + 1e-10f;
    }

    // exclusive prefix product of f over interval index via wave scan
    float pl = f0 * f1;
    float x = pl;
#pragma unroll
    for (int d = 1; d < 64; d <<= 1) {
        float t = __shfl_up(x, d, 64);
        if (lane >= d) x *= t;
    }
    float excl = __shfl_up(x, 1, 64);
    if (lane == 0) excl = 1.0f;
    float w0 = a0 * excl;
    float w1 = a1 * excl * f0;

    float accR = w0 * 0.5f * (r0 + r1) + w1 * 0.5f * (r1 + r2);
    float accG = w0 * 0.5f * (g0 + g1) + w1 * 0.5f * (g1 + g2);
    float accB = w0 * 0.5f * (bb0 + bb1) + w1 * 0.5f * (bb1 + bb2);
    float accD = w0 * 0.5f * (d0 + d1) + w1 * 0.5f * (d1 + d2);
    float accW = w0 + w1;
#pragma unroll
    for (int mask = 1; mask <= 32; mask <<= 1) {
        accR += __shfl_xor(accR, mask, 64);
        accG += __shfl_xor(accG, mask, 64);
        accB += __shfl_xor(accB, mask, 64);
        accD += __shfl_xor(accD, mask, 64);
        accW += __shfl_xor(accW, mask, 64);
    }

    if (lane == 0) {
        float q = accD / accW;
        if (!isfinite(q)) q = 0.0f;
        q = fminf(fmaxf(q, minmax[0]), minmax[1]);
        out[ray * 3 + 0] = accR * 2.0f - 1.0f;
        out[ray * 3 + 1] = accG * 2.0f - 1.0f;
        out[ray * 3 + 2] = accB * 2.0f - 1.0f;
        out[3 * NRAY + ray] = q;
        out[4 * NRAY + ray] = accW;
    }
}

extern "C" void kernel_launch(void* const* d_in, const int* in_sizes, int n_in,
                              void* d_out, int out_size, void* d_ws, size_t ws_size,
                              hipStream_t stream)
{
    const float* planes_tex = (const float*)d_in[0];
    const float* planes_shp = (const float*)d_in[1];
    const float* origins    = (const float*)d_in[2];
    const float* raydirs    = (const float*)d_in[3];
    const float* W1 = (const float*)d_in[4];
    const float* b1 = (const float*)d_in[5];
    const float* W2 = (const float*)d_in[6];
    const float* b2 = (const float*)d_in[7];
    const float* noise = (const float*)d_in[8];
    const float* impu  = (const float*)d_in[9];
    float* out = (float*)d_out;

    // workspace layout (116,391,944 B budget):
    //   [0, 50.3MB)       planes_cl  : interleaved fp16 (6,256,256,64)
    //   [50.3, 100.7MB)   xfeat      : bf16 [NPTS][64]; cdfzm + minmax aliased inside
    //   [100.7MB, ...)    depths_c, depths_f, rgbs_c, rgbs_f
    char* ws = (char*)d_ws;
    __half*         planes_cl = (__half*)ws;
    unsigned short* xfeat     = (unsigned short*)(ws + 50331648);
    float*          cdfzm     = (float*)(ws + 50331648);            // dead before fine gather
    float*          minmax    = (float*)(ws + 50331648 + 8388608);  // written after fine mlp
    float*  depths_c = (float*)(ws + 100663296);
    float*  depths_f = depths_c + NPTS;
    float4* rgbs_c   = (float4*)(depths_f + NPTS);
    float4* rgbs_f   = rgbs_c + NPTS;

    dim3 tb(32, 8);
    transpose_cl<<<dim3(6 * 256 * 8), tb, 0, stream>>>(planes_tex, planes_cl, 0);
    transpose_cl<<<dim3(6 * 256 * 8), tb, 0, stream>>>(planes_shp, planes_cl, 32);
    fill_depths_c<<<dim3((NPTS + 255) / 256), dim3(256), 0, stream>>>(noise, depths_c);

    gather_feat<<<dim3(NPTS / 64), dim3(256), 0, stream>>>(planes_cl, origins, raydirs, depths_c, xfeat);
    mlp_decode<<<dim3(NPTS / 64), dim3(256), 0, stream>>>(xfeat, W1, b1, W2, b2, rgbs_c);

    cdf_build<<<dim3(NRAY / 256), dim3(256), 0, stream>>>(depths_c, rgbs_c, cdfzm);
    imp_sample<<<dim3((NRAY * NI_ + 255) / 256), dim3(256), 0, stream>>>(cdfzm, impu, depths_f);

    gather_feat<<<dim3(NPTS / 64), dim3(256), 0, stream>>>(planes_cl, origins, raydirs, depths_f, xfeat);
    mlp_decode<<<dim3(NPTS / 64), dim3(256), 0, stream>>>(xfeat, W1, b1, W2, b2, rgbs_f);

    minmax_reduce<<<dim3(1), dim3(1024), 0, stream>>>(depths_c, minmax);
    final_march<<<dim3(NRAY / FM_WAVES), dim3(256), 0, stream>>>(depths_c, rgbs_c, depths_f, rgbs_f, minmax, out);
}

// Round 5
// 372.114 us; speedup vs baseline: 5.9274x; 1.2917x over previous
//
#include <hip/hip_runtime.h>
#include <hip/hip_fp16.h>
#include <math.h>

#define NRAY 8192
#define NC_  48
#define NI_  48
#define CPL  32
#define HPL  256
#define HID  64
#define NPTS (NRAY * NC_)        // 393216 points per pass

typedef __attribute__((ext_vector_type(8))) short short8;   // 8 bf16
typedef __attribute__((ext_vector_type(4))) float f32x4;

// fast softplus/sigmoid: v_exp/v_log based; abs error ~1e-7, fine vs 1.55e-2 threshold
__device__ __forceinline__ float softplusf(float x) {
    return fmaxf(x, 0.0f) + __logf(1.0f + __expf(-fabsf(x)));
}
__device__ __forceinline__ float sigmoidf(float x) {
    return 1.0f / (1.0f + __expf(-x));
}
__device__ __forceinline__ unsigned short f2bf(float f) {
    unsigned u = __float_as_uint(f);
    u += 0x7fffu + ((u >> 16) & 1u);
    return (unsigned short)(u >> 16);
}

// ---- transpose (6,32,256,256) fp32 -> interleaved (6,256,256,64) fp16; choff 0=tex,32=shp ----
__global__ void transpose_cl(const float* __restrict__ in, __half* __restrict__ out, int choff) {
    __shared__ float tile[32][33];
    int blk = blockIdx.x;          // p*2048 + y*8 + xt
    int xt = blk & 7;
    int y  = (blk >> 3) & 255;
    int p  = blk >> 11;
    int tx = threadIdx.x;          // 0..31
    int ty = threadIdx.y;          // 0..7
#pragma unroll
    for (int i = 0; i < 4; ++i) {
        int c = ty + 8 * i;
        tile[c][tx] = in[((p * 32 + c) * 256 + y) * 256 + xt * 32 + tx];
    }
    __syncthreads();
#pragma unroll
    for (int i = 0; i < 4; ++i) {
        int xl = ty + 8 * i;
        out[(size_t)(((p * 256 + y) * 256) + xt * 32 + xl) * 64 + choff + tx] = __float2half(tile[tx][xl]);
    }
}

__global__ void fill_depths_c(const float* __restrict__ noise, float* __restrict__ depths) {
    int gid = blockIdx.x * blockDim.x + threadIdx.x;
    if (gid >= NPTS) return;
    int s = gid % NC_;
    const float delta = (1.0f - 0.1f) / (NC_ - 1);
    depths[gid] = 0.1f + delta * (float)s + noise[gid] * delta;
}

// ---- one-time weight fragment prep (1 wave) ----
// w1f: [(t*2+kb)*64 + lane] x 8 bf16   (B-frag: bb[j]=W1[(kb*32+g*8+j)*HID + t*16+c])
// w2f: [t*64 + lane] x 4 floats        (W2[(t*16+c)*4 + o])
// b1f: [t*64 + lane]                   (b1[t*16+c])
__global__ __launch_bounds__(64) void prep_weights(
    const float* __restrict__ W1, const float* __restrict__ b1, const float* __restrict__ W2,
    unsigned short* __restrict__ w1f, float* __restrict__ w2f, float* __restrict__ b1f)
{
    int l = threadIdx.x;
    int g = l >> 4, c = l & 15;
#pragma unroll
    for (int t = 0; t < 4; ++t) {
#pragma unroll
        for (int kb = 0; kb < 2; ++kb)
#pragma unroll
            for (int j = 0; j < 8; ++j)
                w1f[((t * 2 + kb) * 64 + l) * 8 + j] = f2bf(W1[(kb * 32 + g * 8 + j) * HID + t * 16 + c]);
#pragma unroll
        for (int o = 0; o < 4; ++o) w2f[(t * 64 + l) * 4 + o] = W2[(t * 16 + c) * 4 + o];
        b1f[t * 64 + l] = b1[t * 16 + c];
    }
}

// ---- fused plane-gather + MFMA MLP: block = 64 points; LDS feature staging ----
__global__ __launch_bounds__(256) void fused_sample_mlp(
    const __half* __restrict__ planes,     // (6,256,256,64) interleaved fp16
    const float* __restrict__ origins, const float* __restrict__ dirs,
    const float* __restrict__ depths,
    const unsigned short* __restrict__ w1f, const float* __restrict__ w2f,
    const float* __restrict__ b1f, const float* __restrict__ b2,
    float4* __restrict__ outRGBS)
{
    __shared__ unsigned short lds_x[64][72];   // row stride 72 halves (144 B): 16B-aligned, 2-way-max banks

    int tid = threadIdx.x;
    // ---------------- gather phase: 4 threads per point, 16 channels each ----------------
    {
        int pl = tid >> 2, sub = tid & 3;
        int point = blockIdx.x * 64 + pl;
        int ray = point / NC_;
        int bIdx = ray >> 12;

        float ox = origins[ray * 3 + 0], oy = origins[ray * 3 + 1], oz = origins[ray * 3 + 2];
        float dx = dirs[ray * 3 + 0], dy = dirs[ray * 3 + 1], dz = dirs[ray * 3 + 2];
        float invn = 1.0f / sqrtf(dx * dx + dy * dy + dz * dz);
        dx *= invn; dy *= invn; dz *= invn;
        float t = depths[point];
        float px = ox + t * dx, py = oy + t * dy, pz = oz + t * dz;

        float U[3] = {px, px, pz};
        float V[3] = {py, pz, px};

        int   tapOff[12];
        float tapW[12];
        const float inv3 = 1.0f / 3.0f;
#pragma unroll
        for (int pp = 0; pp < 3; ++pp) {
            float gx = (U[pp] + 1.0f) * 128.0f - 0.5f;
            float gy = (V[pp] + 1.0f) * 128.0f - 0.5f;
            float fgx = floorf(gx), fgy = floorf(gy);
            int x0 = (int)fgx, y0 = (int)fgy;
            float fx = gx - fgx, fy = gy - fgy;
#pragma unroll
            for (int k = 0; k < 4; ++k) {
                int dxk = k & 1, dyk = k >> 1;
                int xi = x0 + dxk, yi = y0 + dyk;
                float w = (dxk ? fx : 1.0f - fx) * (dyk ? fy : 1.0f - fy);
                bool valid = (xi >= 0) && (xi < HPL) && (yi >= 0) && (yi < HPL);
                int xc = min(max(xi, 0), HPL - 1);
                int yc = min(max(yi, 0), HPL - 1);
                int p3 = bIdx * 3 + pp;
                tapOff[pp * 4 + k] = (((p3 * HPL) + yc) * HPL + xc) * 64;
                tapW[pp * 4 + k]   = valid ? w * inv3 : 0.0f;
            }
        }

        float acc[16];
#pragma unroll
        for (int i = 0; i < 16; ++i) acc[i] = 0.0f;
#pragma unroll
        for (int kk = 0; kk < 12; ++kk) {
            float w = tapW[kk];
            const float4* pr = (const float4*)(planes + tapOff[kk] + sub * 16);
            float4 v0 = pr[0], v1 = pr[1];
            union { float4 f; __half2 h[4]; } u0, u1;
            u0.f = v0; u1.f = v1;
#pragma unroll
            for (int i = 0; i < 4; ++i) {
                float2 f0 = __half22float2(u0.h[i]);
                float2 f1 = __half22float2(u1.h[i]);
                acc[2 * i]         = fmaf(w, f0.x, acc[2 * i]);
                acc[2 * i + 1]     = fmaf(w, f0.y, acc[2 * i + 1]);
                acc[8 + 2 * i]     = fmaf(w, f1.x, acc[8 + 2 * i]);
                acc[8 + 2 * i + 1] = fmaf(w, f1.y, acc[8 + 2 * i + 1]);
            }
        }
        unsigned short u16[16];
#pragma unroll
        for (int i = 0; i < 16; ++i) u16[i] = f2bf(acc[i]);
        uint4* dst = (uint4*)&lds_x[pl][sub * 16];
        dst[0] = *(uint4*)(u16);
        dst[1] = *(uint4*)(u16 + 8);
    }
    __syncthreads();

    // ---------------- MFMA MLP phase: each wave owns its 16 points ----------------
    int lane = tid & 63, wave = tid >> 6;
    int g = lane >> 4, c = lane & 15;
    int m0 = blockIdx.x * 64 + wave * 16;

    short8 bfr[4][2];
#pragma unroll
    for (int t = 0; t < 4; ++t)
#pragma unroll
        for (int kb = 0; kb < 2; ++kb)
            bfr[t][kb] = *(const short8*)(w1f + ((size_t)((t * 2 + kb) * 64 + lane)) * 8);
    float4 w2v[4];
    float  b1v[4];
#pragma unroll
    for (int t = 0; t < 4; ++t) {
        w2v[t] = *(const float4*)(w2f + (size_t)(t * 64 + lane) * 4);
        b1v[t] = b1f[t * 64 + lane];
    }

    int mrow = wave * 16 + c;
    short8 a0 = *(const short8*)(&lds_x[mrow][g * 8]);
    short8 a1 = *(const short8*)(&lds_x[mrow][32 + g * 8]);

    f32x4 accv[4];
#pragma unroll
    for (int t = 0; t < 4; ++t) {
        f32x4 z = {0.f, 0.f, 0.f, 0.f};
        z = __builtin_amdgcn_mfma_f32_16x16x32_bf16(a0, bfr[t][0], z, 0, 0, 0);
        z = __builtin_amdgcn_mfma_f32_16x16x32_bf16(a1, bfr[t][1], z, 0, 0, 0);
        accv[t] = z;
    }

    float o[4][4];
#pragma unroll
    for (int r = 0; r < 4; ++r)
#pragma unroll
        for (int q = 0; q < 4; ++q) o[r][q] = 0.0f;
#pragma unroll
    for (int t = 0; t < 4; ++t)
#pragma unroll
        for (int r = 0; r < 4; ++r) {
            float h = accv[t][r] + b1v[t];
            float sp = softplusf(h);
            o[r][0] = fmaf(sp, w2v[t].x, o[r][0]);
            o[r][1] = fmaf(sp, w2v[t].y, o[r][1]);
            o[r][2] = fmaf(sp, w2v[t].z, o[r][2]);
            o[r][3] = fmaf(sp, w2v[t].w, o[r][3]);
        }
#pragma unroll
    for (int mask = 1; mask <= 8; mask <<= 1)
#pragma unroll
        for (int r = 0; r < 4; ++r)
#pragma unroll
            for (int q = 0; q < 4; ++q) o[r][q] += __shfl_xor(o[r][q], mask, 64);

    if (c == 0) {
#pragma unroll
        for (int r = 0; r < 4; ++r) {
            int pt = m0 + g * 4 + r;
            float sig = o[r][0] + b2[0];
            float rr = sigmoidf(o[r][1] + b2[1]) * 1.002f - 0.001f;
            float gg = sigmoidf(o[r][2] + b2[2]) * 1.002f - 0.001f;
            float bb = sigmoidf(o[r][3] + b2[3]) * 1.002f - 0.001f;
            outRGBS[pt] = make_float4(rr, gg, bb, sig);
        }
    }
}

// ---- coarse march -> cdf + z_mid per ray (stride 96: [0..45]=cdf, [46..92]=zm) ----
__global__ void cdf_build(const float* __restrict__ depths_c,
                          const float4* __restrict__ rgbs_c,
                          float* __restrict__ cdfzm)
{
    int ray = blockIdx.x * blockDim.x + threadIdx.x;
    if (ray >= NRAY) return;
    float w[NC_ - 1];
    float* outz = cdfzm + (size_t)ray * 96 + 46;
    float T = 1.0f;
    float dprev = depths_c[ray * NC_], sprev = rgbs_c[ray * NC_].w;
#pragma unroll
    for (int i = 0; i < NC_ - 1; ++i) {
        float dn = depths_c[ray * NC_ + i + 1];
        float sn = rgbs_c[ray * NC_ + i + 1].w;
        outz[i] = 0.5f * (dprev + dn);
        float dl = dn - dprev;
        float dens = softplusf(0.5f * (sprev + sn) - 1.0f);
        float alpha = 1.0f - __expf(-dens * dl);
        w[i] = alpha * T;
        T *= (1.0f - alpha + 1e-10f);
        dprev = dn; sprev = sn;
    }
    float wmax[NC_];
    wmax[0] = w[0];
#pragma unroll
    for (int i = 1; i < NC_ - 1; ++i) wmax[i] = fmaxf(w[i - 1], w[i]);
    wmax[NC_ - 1] = w[NC_ - 2];
    float wbv[NC_ - 1];
#pragma unroll
    for (int i = 0; i < NC_ - 1; ++i) wbv[i] = 0.5f * (wmax[i] + wmax[i + 1]) + 0.01f;
    float s = 0.0f;
#pragma unroll
    for (int i = 1; i <= 45; ++i) s += wbv[i];
    float* outc = cdfzm + (size_t)ray * 96;
    outc[0] = 0.0f;
    float cum = 0.0f;
#pragma unroll
    for (int i = 1; i <= 45; ++i) { cum += wbv[i] / s; outc[i] = cum; }
}

// ---- importance sampling: one thread per (ray, q) ----
__global__ void imp_sample(const float* __restrict__ cdfzm,
                           const float* __restrict__ impu,
                           float* __restrict__ depths_f)
{
    int gid = blockIdx.x * blockDim.x + threadIdx.x;
    if (gid >= NRAY * NI_) return;
    int ray = gid / NI_;
    const float* cdf = cdfzm + (size_t)ray * 96;
    const float* zm  = cdf + 46;
    float u = impu[gid];
    int lo = 0, hi = 46;
    while (lo < hi) { int mid = (lo + hi) >> 1; if (cdf[mid] > u) hi = mid; else lo = mid + 1; }
    int below = max(lo - 1, 0);
    int above = min(lo, 45);
    float c0 = cdf[below], c1 = cdf[above];
    float b0 = zm[below], b1v = zm[above];
    float den = c1 - c0; if (den < 1e-5f) den = 1.0f;
    depths_f[gid] = b0 + (u - c0) / den * (b1v - b0);
}

// ---- global depth min/max (single block) ----
__global__ __launch_bounds__(1024) void minmax_reduce(const float* __restrict__ depths_c,
                                                      float* __restrict__ minmax)
{
    int tid = threadIdx.x;
    float mn = INFINITY, mx = -INFINITY;
    for (int r = tid; r < NRAY; r += 1024) {
        mn = fminf(mn, depths_c[r * NC_]);
        mx = fmaxf(mx, depths_c[r * NC_ + NC_ - 1]);
    }
#pragma unroll
    for (int mask = 1; mask <= 32; mask <<= 1) {
        mn = fminf(mn, __shfl_xor(mn, mask, 64));
        mx = fmaxf(mx, __shfl_xor(mx, mask, 64));
    }
    __shared__ float smn[16], smx[16];
    if ((tid & 63) == 0) { smn[tid >> 6] = mn; smx[tid >> 6] = mx; }
    __syncthreads();
    if (tid == 0) {
        for (int i = 1; i < 16; ++i) { mn = fminf(mn, smn[i]); mx = fmaxf(mx, smx[i]); }
        minmax[0] = mn; minmax[1] = mx;
    }
}

// ---- merge + final march: ONE WAVE PER RAY, lane-parallel rank-merge + scan ----
#define FM_WAVES 4
__global__ __launch_bounds__(256) void final_march(
    const float* __restrict__ depths_c, const float4* __restrict__ rgbs_c,
    const float* __restrict__ depths_f, const float4* __restrict__ rgbs_f,
    const float* __restrict__ minmax, float* __restrict__ out)
{
    __shared__ float s_dc[FM_WAVES][NC_];
    __shared__ float s_df[FM_WAVES][NI_];
    __shared__ float s_md[FM_WAVES][96];
    __shared__ float s_ms[FM_WAVES][96];
    __shared__ float s_mr[FM_WAVES][96];
    __shared__ float s_mg[FM_WAVES][96];
    __shared__ float s_mb[FM_WAVES][96];

    int wave = threadIdx.x >> 6, lane = threadIdx.x & 63;
    int ray = blockIdx.x * FM_WAVES + wave;
    float* dcp = s_dc[wave];
    float* dfp = s_df[wave];
    float* mdp = s_md[wave];
    float* msp = s_ms[wave];
    float* mrp = s_mr[wave];
    float* mgp = s_mg[wave];
    float* mbp = s_mb[wave];

    float dcv = 0.f, dfv = 0.f;
    float4 c4 = make_float4(0, 0, 0, 0), f4 = make_float4(0, 0, 0, 0);
    if (lane < NC_) {
        dcv = depths_c[ray * NC_ + lane];
        dfv = depths_f[ray * NI_ + lane];
        dcp[lane] = dcv;
        dfp[lane] = dfv;
        c4 = rgbs_c[ray * NC_ + lane];
        f4 = rgbs_f[ray * NI_ + lane];
    }
    __syncthreads();

    if (lane < NC_) {
        int cntC = 0, rankF = 0, cntCle = 0;
#pragma unroll
        for (int j = 0; j < NC_; ++j) {
            float dfj = dfp[j];
            float dcj = dcp[j];
            cntC   += (dfj < dcv) ? 1 : 0;
            rankF  += ((dfj < dfv) || (dfj == dfv && j < lane)) ? 1 : 0;
            cntCle += (dcj <= dfv) ? 1 : 0;
        }
        int posC = lane + cntC;          // stable: coarse before equal fine
        int posF = rankF + cntCle;
        mdp[posC] = dcv; msp[posC] = c4.w; mrp[posC] = c4.x; mgp[posC] = c4.y; mbp[posC] = c4.z;
        mdp[posF] = dfv; msp[posF] = f4.w; mrp[posF] = f4.x; mgp[posF] = f4.y; mbp[posF] = f4.z;
    }
    __syncthreads();

    int k0 = 2 * lane;
    int i0 = min(k0, 95), i1 = min(k0 + 1, 95), i2 = min(k0 + 2, 95);
    float d0 = mdp[i0], d1 = mdp[i1], d2 = mdp[i2];
    float sg0 = msp[i0], sg1 = msp[i1], sg2 = msp[i2];
    float r0 = mrp[i0], r1 = mrp[i1], r2 = mrp[i2];
    float g0 = mgp[i0], g1 = mgp[i1], g2 = mgp[i2];
    float bb0 = mbp[i0], bb1 = mbp[i1], bb2 = mbp[i2];

    bool v0 = (k0 < 95), v1 = (k0 + 1 < 95);
    float a0 = 0.f, a1 = 0.f, f0 = 1.f, f1 = 1.f;
    if (v0) {
        float dens = softplusf(0.5f * (sg0 + sg1) - 1.0f);
        a0 = 1.0f - __expf(-dens * (d1 - d0));
        f0 = 1.0f - a0 + 1e-10f;
    }
    if (v1) {
        float dens = softplusf(0.5f * (sg1 + sg2) - 1.0f);
        a1 = 1.0f - __expf(-dens * (d2 - d1));
        f1 = 1.0f - a1 + 1e-10f;
    }

    float pl = f0 * f1;
    float x = pl;
#pragma unroll
    for (int d = 1; d < 64; d <<= 1) {
        float t = __shfl_up(x, d, 64);
        if (lane >= d) x *= t;
    }
    float excl = __shfl_up(x, 1, 64);
    if (lane == 0) excl = 1.0f;
    float w0 = a0 * excl;
    float w1 = a1 * excl * f0;

    float accR = w0 * 0.5f * (r0 + r1) + w1 * 0.5f * (r1 + r2);
    float accG = w0 * 0.5f * (g0 + g1) + w1 * 0.5f * (g1 + g2);
    float accB = w0 * 0.5f * (bb0 + bb1) + w1 * 0.5f * (bb1 + bb2);
    float accD = w0 * 0.5f * (d0 + d1) + w1 * 0.5f * (d1 + d2);
    float accW = w0 + w1;
#pragma unroll
    for (int mask = 1; mask <= 32; mask <<= 1) {
        accR += __shfl_xor(accR, mask, 64);
        accG += __shfl_xor(accG, mask, 64);
        accB += __shfl_xor(accB, mask, 64);
        accD += __shfl_xor(accD, mask, 64);
        accW += __shfl_xor(accW, mask, 64);
    }

    if (lane == 0) {
        float q = accD / accW;
        if (!isfinite(q)) q = 0.0f;
        q = fminf(fmaxf(q, minmax[0]), minmax[1]);
        out[ray * 3 + 0] = accR * 2.0f - 1.0f;
        out[ray * 3 + 1] = accG * 2.0f - 1.0f;
        out[ray * 3 + 2] = accB * 2.0f - 1.0f;
        out[3 * NRAY + ray] = q;
        out[4 * NRAY + ray] = accW;
    }
}

extern "C" void kernel_launch(void* const* d_in, const int* in_sizes, int n_in,
                              void* d_out, int out_size, void* d_ws, size_t ws_size,
                              hipStream_t stream)
{
    const float* planes_tex = (const float*)d_in[0];
    const float* planes_shp = (const float*)d_in[1];
    const float* origins    = (const float*)d_in[2];
    const float* raydirs    = (const float*)d_in[3];
    const float* W1 = (const float*)d_in[4];
    const float* b1 = (const float*)d_in[5];
    const float* W2 = (const float*)d_in[6];
    const float* b2 = (const float*)d_in[7];
    const float* noise = (const float*)d_in[8];
    const float* impu  = (const float*)d_in[9];
    float* out = (float*)d_out;

    // workspace layout (~70 MB of the 116 MB budget):
    char* ws = (char*)d_ws;
    __half*         planes_cl = (__half*)ws;                          // 50,331,648 B
    unsigned short* w1f       = (unsigned short*)(ws + 50331648);     // 8,192 B
    float*          w2f       = (float*)(ws + 50339840);              // 4,096 B
    float*          b1f       = (float*)(ws + 50343936);              // 1,024 B
    float*          cdfzm     = (float*)(ws + 50348032);              // 3,145,728 B
    float*          minmax    = (float*)(ws + 53493760);              // 8 B (+pad)
    float*  depths_c = (float*)(ws + 53494016);                       // 1,572,864 B
    float*  depths_f = depths_c + NPTS;                               // 1,572,864 B
    float4* rgbs_c   = (float4*)(depths_f + NPTS);                    // 6,291,456 B
    float4* rgbs_f   = rgbs_c + NPTS;                                 // 6,291,456 B

    dim3 tb(32, 8);
    transpose_cl<<<dim3(6 * 256 * 8), tb, 0, stream>>>(planes_tex, planes_cl, 0);
    transpose_cl<<<dim3(6 * 256 * 8), tb, 0, stream>>>(planes_shp, planes_cl, 32);
    prep_weights<<<dim3(1), dim3(64), 0, stream>>>(W1, b1, W2, w1f, w2f, b1f);
    fill_depths_c<<<dim3((NPTS + 255) / 256), dim3(256), 0, stream>>>(noise, depths_c);

    fused_sample_mlp<<<dim3(NPTS / 64), dim3(256), 0, stream>>>(
        planes_cl, origins, raydirs, depths_c, w1f, w2f, b1f, b2, rgbs_c);

    cdf_build<<<dim3(NRAY / 256), dim3(256), 0, stream>>>(depths_c, rgbs_c, cdfzm);
    imp_sample<<<dim3((NRAY * NI_ + 255) / 256), dim3(256), 0, stream>>>(cdfzm, impu, depths_f);

    fused_sample_mlp<<<dim3(NPTS / 64), dim3(256), 0, stream>>>(
        planes_cl, origins, raydirs, depths_f, w1f, w2f, b1f, b2, rgbs_f);

    minmax_reduce<<<dim3(1), dim3(1024), 0, stream>>>(depths_c, minmax);
    final_march<<<dim3(NRAY / FM_WAVES), dim3(256), 0, stream>>>(depths_c, rgbs_c, depths_f, rgbs_f, minmax, out);
}